// Round 1
// baseline (581.098 us; speedup 1.0000x reference)
//
#include <hip/hip_runtime.h>
#include <hip/hip_bf16.h>

typedef __attribute__((ext_vector_type(8))) short short8;

static __device__ __forceinline__ float bflo(unsigned u){ return __uint_as_float(u << 16); }
static __device__ __forceinline__ float bfhi(unsigned u){ return __uint_as_float(u & 0xffff0000u); }
static __device__ __forceinline__ unsigned short f2bf(float f){
  unsigned u = __float_as_uint(f);
  unsigned r = u + 0x7fffu + ((u >> 16) & 1u);
  return (unsigned short)(r >> 16);
}

// ---------------- graph preprocessing ----------------

__global__ __launch_bounds__(256) void k_hist(const int* __restrict__ dst, int* __restrict__ cnt, int E){
  int e = blockIdx.x * 256 + threadIdx.x;
  if (e < E) atomicAdd(&cnt[dst[e]], 1);
}

__global__ __launch_bounds__(256) void k_dinv(const int* __restrict__ cnt, float* __restrict__ dinv, int n){
  int i = blockIdx.x * 256 + threadIdx.x;
  if (i < n) dinv[i] = rsqrtf((float)(cnt[i] + 1));   // +1 self loop, always > 0
}

// exclusive scan of cnt[0..n) -> rowptr, 1024 items per block
__global__ __launch_bounds__(256) void k_scan1(const int* __restrict__ cnt, int* __restrict__ rowptr,
                                               int* __restrict__ blk, int n){
  __shared__ int lds[256];
  int t = threadIdx.x;
  int base = blockIdx.x * 1024 + t * 4;
  int v0 = 0, v1 = 0, v2 = 0, v3 = 0;
  if (base + 3 < n) { int4 v = *(const int4*)(cnt + base); v0 = v.x; v1 = v.y; v2 = v.z; v3 = v.w; }
  else {
    if (base     < n) v0 = cnt[base];
    if (base + 1 < n) v1 = cnt[base + 1];
    if (base + 2 < n) v2 = cnt[base + 2];
  }
  int s = v0 + v1 + v2 + v3;
  lds[t] = s; __syncthreads();
  for (int off = 1; off < 256; off <<= 1){
    int u = (t >= off) ? lds[t - off] : 0;
    __syncthreads();
    lds[t] += u;
    __syncthreads();
  }
  int incl = lds[t];
  int r = incl - s;          // exclusive prefix for this thread's first item
  if (base     < n) rowptr[base]     = r;  r += v0;
  if (base + 1 < n) rowptr[base + 1] = r;  r += v1;
  if (base + 2 < n) rowptr[base + 2] = r;  r += v2;
  if (base + 3 < n) rowptr[base + 3] = r;
  if (t == 255) blk[blockIdx.x] = incl;    // block total
}

__global__ __launch_bounds__(256) void k_scan2(int* __restrict__ blk, int nb){
  __shared__ int lds[256];
  int t = threadIdx.x;
  int s = (t < nb) ? blk[t] : 0;
  lds[t] = s; __syncthreads();
  for (int off = 1; off < 256; off <<= 1){
    int u = (t >= off) ? lds[t - off] : 0;
    __syncthreads();
    lds[t] += u;
    __syncthreads();
  }
  if (t < nb) blk[t] = lds[t] - s;         // exclusive
}

__global__ __launch_bounds__(256) void k_scan3(int* __restrict__ rowptr, const int* __restrict__ blk,
                                               int n, int E){
  int add = blk[blockIdx.x];
  int base = blockIdx.x * 1024 + threadIdx.x * 4;
  #pragma unroll
  for (int j = 0; j < 4; j++) if (base + j < n) rowptr[base + j] += add;
  if (blockIdx.x == 0 && threadIdx.x == 0) rowptr[n] = E;
}

__global__ __launch_bounds__(256) void k_scatter(const int* __restrict__ src, const int* __restrict__ dst,
    const int* __restrict__ rowptr, int* __restrict__ cnt, int* __restrict__ colv, int E){
  int e = blockIdx.x * 256 + threadIdx.x;
  if (e >= E) return;
  int d = dst[e];
  int p = rowptr[d] + atomicAdd(&cnt[d], 1);
  colv[p] = src[e];
}

// ---------------- GEMM: G[i,:] = bf16( dinv[i] * (A[i,:] @ W) ) ----------------
// 512 threads, 128 rows/block, per-thread 4 rows x 8 cols. W(64KB) + A-tile(66KB) in LDS.

__global__ __launch_bounds__(512) void k_gemm(const float* __restrict__ A, const float* __restrict__ W,
    const float* __restrict__ dinv, unsigned short* __restrict__ G, int n)
{
  __shared__ float Ws[128 * 128];
  __shared__ float As[128 * 132];
  const int t = threadIdx.x;
  const int rowBase = blockIdx.x * 128;
  {
    const float4* Wv = (const float4*)W;
    float4* Wsv = (float4*)Ws;
    #pragma unroll
    for (int j = 0; j < 8; j++) Wsv[t + j * 512] = Wv[t + j * 512];
  }
  {
    #pragma unroll
    for (int j = 0; j < 8; j++){
      int id = t + j * 512;
      int r = id >> 5, c4 = id & 31;
      int gr = rowBase + r;
      float4 v = make_float4(0.f, 0.f, 0.f, 0.f);
      if (gr < n) v = *(const float4*)(A + (size_t)gr * 128 + c4 * 4);
      *(float4*)(&As[r * 132 + c4 * 4]) = v;
    }
  }
  __syncthreads();

  const int ci = t & 15;         // 8-col group
  const int r0 = (t >> 4) * 4;   // first of 4 rows
  float acc[4][8];
  #pragma unroll
  for (int i = 0; i < 4; i++)
    #pragma unroll
    for (int j = 0; j < 8; j++) acc[i][j] = 0.f;

  const float* WsC = Ws + ci * 8;
  #pragma unroll 4
  for (int k = 0; k < 128; k++){
    float4 wa = *(const float4*)(WsC + k * 128);
    float4 wb = *(const float4*)(WsC + k * 128 + 4);
    float a0 = As[(r0    ) * 132 + k];
    float a1 = As[(r0 + 1) * 132 + k];
    float a2 = As[(r0 + 2) * 132 + k];
    float a3 = As[(r0 + 3) * 132 + k];
    float wv[8] = {wa.x, wa.y, wa.z, wa.w, wb.x, wb.y, wb.z, wb.w};
    float av[4] = {a0, a1, a2, a3};
    #pragma unroll
    for (int i = 0; i < 4; i++)
      #pragma unroll
      for (int j = 0; j < 8; j++)
        acc[i][j] = fmaf(av[i], wv[j], acc[i][j]);
  }

  #pragma unroll
  for (int i = 0; i < 4; i++){
    int gr = rowBase + r0 + i;
    if (gr >= n) continue;
    float dv = dinv[gr];
    short8 o;
    #pragma unroll
    for (int j = 0; j < 8; j++) o[j] = (short)f2bf(dv * acc[i][j]);
    *reinterpret_cast<short8*>(G + (size_t)gr * 128 + ci * 8) = o;
  }
}

// ---------------- SpMM: H[d,:] = relu( dinv[d] * (sum_{s in N(d)} G[s,:] + G[d,:]) + b ) ----------------
// one wave per dst row, 2 features per lane (bf16 pair per dword)

__global__ __launch_bounds__(256) void k_spmm(const unsigned* __restrict__ G, const int* __restrict__ rowptr,
    const int* __restrict__ colv, const float* __restrict__ dinv, const float* __restrict__ bias,
    float* __restrict__ H, int n)
{
  int wid  = (blockIdx.x * 256 + threadIdx.x) >> 6;
  int lane = threadIdx.x & 63;
  if (wid >= n) return;
  unsigned u = G[(size_t)wid * 64 + lane];          // self loop
  float acc0 = bflo(u), acc1 = bfhi(u);
  int e = rowptr[wid], e1 = rowptr[wid + 1];
  for (; e + 4 <= e1; e += 4){
    int s0 = colv[e], s1 = colv[e + 1], s2 = colv[e + 2], s3 = colv[e + 3];
    unsigned a = G[(size_t)s0 * 64 + lane];
    unsigned b = G[(size_t)s1 * 64 + lane];
    unsigned c = G[(size_t)s2 * 64 + lane];
    unsigned d = G[(size_t)s3 * 64 + lane];
    acc0 += bflo(a) + bflo(b) + bflo(c) + bflo(d);
    acc1 += bfhi(a) + bfhi(b) + bfhi(c) + bfhi(d);
  }
  for (; e < e1; ++e){
    unsigned a = G[(size_t)colv[e] * 64 + lane];
    acc0 += bflo(a); acc1 += bfhi(a);
  }
  float dv = dinv[wid];
  float r0 = fmaxf(fmaf(dv, acc0, bias[lane * 2    ]), 0.f);
  float r1 = fmaxf(fmaf(dv, acc1, bias[lane * 2 + 1]), 0.f);
  *reinterpret_cast<float2*>(H + (size_t)wid * 128 + lane * 2) = make_float2(r0, r1);
}

// ---------------- layer 3: scalar pipeline ----------------

__global__ __launch_bounds__(256) void k_gemv3(const float* __restrict__ H, const float* __restrict__ W3,
    const float* __restrict__ dinv, float* __restrict__ tvec, float* __restrict__ aggv, int n)
{
  int wid  = (blockIdx.x * 256 + threadIdx.x) >> 6;
  int lane = threadIdx.x & 63;
  if (wid >= n) return;
  float2 h = *(const float2*)(H + (size_t)wid * 128 + lane * 2);
  float2 w = *(const float2*)(W3 + lane * 2);
  float v = h.x * w.x + h.y * w.y;
  #pragma unroll
  for (int off = 32; off; off >>= 1) v += __shfl_xor(v, off);
  if (lane == 0){
    float tv = dinv[wid] * v;
    tvec[wid] = tv;
    aggv[wid] = tv;      // self loop init
  }
}

__global__ __launch_bounds__(256) void k_edge3(const int* __restrict__ src, const int* __restrict__ dst,
    const float* __restrict__ tvec, float* __restrict__ aggv, int E)
{
  int e = blockIdx.x * 256 + threadIdx.x;
  if (e < E) atomicAdd(&aggv[dst[e]], tvec[src[e]]);
}

__global__ __launch_bounds__(256) void k_final(const float* __restrict__ aggv, const float* __restrict__ dinv,
    const float* __restrict__ b3, const float* __restrict__ x, float* __restrict__ out, int n)
{
  int i = blockIdx.x * 256 + threadIdx.x;
  if (i >= n) return;
  float v = fmaxf(fmaf(dinv[i], aggv[i], b3[0]), 0.f);
  out[i] = v + x[(size_t)i * 128 + 127];   // residual: x[:, -1]
}

// ---------------- launch ----------------

extern "C" void kernel_launch(void* const* d_in, const int* in_sizes, int n_in,
                              void* d_out, int out_size, void* d_ws, size_t ws_size,
                              hipStream_t stream)
{
  const float* x  = (const float*)d_in[0];
  const int*   ei = (const int*)d_in[1];
  const float* W1 = (const float*)d_in[3];
  const float* b1 = (const float*)d_in[4];
  const float* W2 = (const float*)d_in[5];
  const float* b2 = (const float*)d_in[6];
  const float* W3 = (const float*)d_in[7];
  const float* b3 = (const float*)d_in[8];
  float* out = (float*)d_out;

  const int N = in_sizes[0] / 128;
  const int E = in_sizes[1] / 2;
  const int* src = ei;
  const int* dst = ei + E;

  char* wsb = (char*)d_ws;
  size_t off = 0;
  auto carve = [&](size_t bytes) -> void* {
    void* p = wsb + off;
    off += bytes;
    off = (off + 255) & ~(size_t)255;
    return p;
  };
  float*    dinv   = (float*)carve((size_t)N * 4);
  int*      cnt    = (int*)carve((size_t)N * 4);
  int*      rowptr = (int*)carve((size_t)(N + 1) * 4);
  int*      colv   = (int*)carve((size_t)E * 4);
  int*      blk    = (int*)carve(4096);
  float*    tvec   = (float*)carve((size_t)N * 4);
  float*    aggv   = (float*)carve((size_t)N * 4);
  unsigned* G      = (unsigned*)carve((size_t)N * 256);  // bf16 N x 128
  float*    H      = (float*)carve((size_t)N * 512);     // f32  N x 128

  const int nB = (N + 1023) / 1024;   // scan blocks (<= 256)

  hipMemsetAsync(cnt, 0, (size_t)N * 4, stream);
  k_hist   <<<(E + 255) / 256, 256, 0, stream>>>(dst, cnt, E);
  k_dinv   <<<(N + 255) / 256, 256, 0, stream>>>(cnt, dinv, N);
  k_scan1  <<<nB, 256, 0, stream>>>(cnt, rowptr, blk, N);
  k_scan2  <<<1, 256, 0, stream>>>(blk, nB);
  k_scan3  <<<nB, 256, 0, stream>>>(rowptr, blk, N, E);
  hipMemsetAsync(cnt, 0, (size_t)N * 4, stream);
  k_scatter<<<(E + 255) / 256, 256, 0, stream>>>(src, dst, rowptr, cnt, colv, E);

  // layer 1
  k_gemm<<<(N + 127) / 128, 512, 0, stream>>>(x, W1, dinv, (unsigned short*)G, N);
  k_spmm<<<(N + 3) / 4, 256, 0, stream>>>(G, rowptr, colv, dinv, b1, H, N);
  // layer 2
  k_gemm<<<(N + 127) / 128, 512, 0, stream>>>(H, W2, dinv, (unsigned short*)G, N);
  k_spmm<<<(N + 3) / 4, 256, 0, stream>>>(G, rowptr, colv, dinv, b2, H, N);
  // layer 3 (HID -> 1)
  k_gemv3<<<(N + 3) / 4, 256, 0, stream>>>(H, W3, dinv, tvec, aggv, N);
  k_edge3<<<(E + 255) / 256, 256, 0, stream>>>(src, dst, tvec, aggv, E);
  k_final<<<(N + 255) / 256, 256, 0, stream>>>(aggv, dinv, b3, x, out, N);
}

// Round 2
// 500.081 us; speedup vs baseline: 1.1620x; 1.1620x over previous
//
#include <hip/hip_runtime.h>
#include <hip/hip_bf16.h>

typedef __attribute__((ext_vector_type(8))) short short8;

static __device__ __forceinline__ float bflo(unsigned u){ return __uint_as_float(u << 16); }
static __device__ __forceinline__ float bfhi(unsigned u){ return __uint_as_float(u & 0xffff0000u); }
static __device__ __forceinline__ unsigned short f2bf(float f){
  unsigned u = __float_as_uint(f);
  unsigned r = u + 0x7fffu + ((u >> 16) & 1u);
  return (unsigned short)(r >> 16);
}

// ---------------- graph preprocessing ----------------

__global__ __launch_bounds__(256) void k_hist(const int* __restrict__ dst, int* __restrict__ cnt, int E){
  int e = blockIdx.x * 256 + threadIdx.x;
  if (e < E) atomicAdd(&cnt[dst[e]], 1);
}

__global__ __launch_bounds__(256) void k_dinv(const int* __restrict__ cnt, float* __restrict__ dinv, int n){
  int i = blockIdx.x * 256 + threadIdx.x;
  if (i < n) dinv[i] = rsqrtf((float)(cnt[i] + 1));   // +1 self loop, always > 0
}

// exclusive scan of cnt[0..n) -> rowptr, 1024 items per block
__global__ __launch_bounds__(256) void k_scan1(const int* __restrict__ cnt, int* __restrict__ rowptr,
                                               int* __restrict__ blk, int n){
  __shared__ int lds[256];
  int t = threadIdx.x;
  int base = blockIdx.x * 1024 + t * 4;
  int v0 = 0, v1 = 0, v2 = 0, v3 = 0;
  if (base + 3 < n) { int4 v = *(const int4*)(cnt + base); v0 = v.x; v1 = v.y; v2 = v.z; v3 = v.w; }
  else {
    if (base     < n) v0 = cnt[base];
    if (base + 1 < n) v1 = cnt[base + 1];
    if (base + 2 < n) v2 = cnt[base + 2];
  }
  int s = v0 + v1 + v2 + v3;
  lds[t] = s; __syncthreads();
  for (int off = 1; off < 256; off <<= 1){
    int u = (t >= off) ? lds[t - off] : 0;
    __syncthreads();
    lds[t] += u;
    __syncthreads();
  }
  int incl = lds[t];
  int r = incl - s;
  if (base     < n) rowptr[base]     = r;  r += v0;
  if (base + 1 < n) rowptr[base + 1] = r;  r += v1;
  if (base + 2 < n) rowptr[base + 2] = r;  r += v2;
  if (base + 3 < n) rowptr[base + 3] = r;
  if (t == 255) blk[blockIdx.x] = incl;
}

__global__ __launch_bounds__(256) void k_scan2(int* __restrict__ blk, int nb){
  __shared__ int lds[256];
  int t = threadIdx.x;
  int s = (t < nb) ? blk[t] : 0;
  lds[t] = s; __syncthreads();
  for (int off = 1; off < 256; off <<= 1){
    int u = (t >= off) ? lds[t - off] : 0;
    __syncthreads();
    lds[t] += u;
    __syncthreads();
  }
  if (t < nb) blk[t] = lds[t] - s;
}

__global__ __launch_bounds__(256) void k_scan3(int* __restrict__ rowptr, const int* __restrict__ blk,
                                               int n, int E){
  int add = blk[blockIdx.x];
  int base = blockIdx.x * 1024 + threadIdx.x * 4;
  #pragma unroll
  for (int j = 0; j < 4; j++) if (base + j < n) rowptr[base + j] += add;
  if (blockIdx.x == 0 && threadIdx.x == 0) rowptr[n] = E;
}

// bpos[b] = start offset of bucket b's segment in colv/ebuf
__global__ __launch_bounds__(256) void k_binit(const int* __restrict__ rowptr, int* __restrict__ bpos, int nb){
  int b = blockIdx.x * 256 + threadIdx.x;
  if (b < nb) bpos[b] = rowptr[b << 7];
}

// ---- partition pass: 8192 edges/block, bucket by dst>>7, LDS-staged coalesced writes ----
#define PART_C 8192
#define NBMAX  1024

__global__ __launch_bounds__(1024) void k_part(const int* __restrict__ src, const int* __restrict__ dst,
    int* __restrict__ bpos, unsigned* __restrict__ ebuf, int E, int NB)
{
  __shared__ int hist[NBMAX + 1];   // pass1 counts -> exclusive scan (+ total sentinel)
  __shared__ int hist2[NBMAX];      // pass2 ranks
  __shared__ int gbase[NBMAX];      // global reservation per bucket
  __shared__ int sc[1024];          // scan scratch
  __shared__ unsigned staged[PART_C];

  const int t = threadIdx.x;
  const int base = blockIdx.x * PART_C;

  for (int i = t; i < NBMAX; i += 1024){ hist[i] = 0; hist2[i] = 0; }
  __syncthreads();

  unsigned up[8];
  int bb[8];
  #pragma unroll
  for (int j = 0; j < 8; j++){
    int e = base + j * 1024 + t;
    if (e < E){
      int s = src[e], d = dst[e];
      bb[j] = d >> 7;
      up[j] = ((unsigned)s << 7) | (unsigned)(d & 127);
      atomicAdd(&hist[bb[j]], 1);
    } else bb[j] = -1;
  }
  __syncthreads();

  // exclusive scan of hist[0..NB)
  int v = (t < NB) ? hist[t] : 0;
  sc[t] = v; __syncthreads();
  for (int off = 1; off < 1024; off <<= 1){
    int u = (t >= off) ? sc[t - off] : 0;
    __syncthreads();
    sc[t] += u;
    __syncthreads();
  }
  int incl = sc[t];
  if (t < NB) hist[t] = incl - v;
  if (t == NB - 1) hist[NB] = incl;       // total edges this block
  // reserve global space
  if (t < NB && v > 0) gbase[t] = atomicAdd(&bpos[t], v);
  __syncthreads();

  // stage in bucket order
  #pragma unroll
  for (int j = 0; j < 8; j++){
    if (bb[j] >= 0){
      int r = atomicAdd(&hist2[bb[j]], 1);
      staged[hist[bb[j]] + r] = up[j];
    }
  }
  __syncthreads();

  // linear write-out: binary search bucket for index i
  int total = hist[NB];
  for (int i = t; i < total; i += 1024){
    int lo = 0, hi = NB;
    while (hi - lo > 1){
      int mid = (lo + hi) >> 1;
      if (hist[mid] <= i) lo = mid; else hi = mid;
    }
    ebuf[gbase[lo] + (i - hist[lo])] = staged[i];
  }
}

// ---- fine sort within each 128-row bucket: coalesced colv writes ----
#define STCAP 4096

__global__ __launch_bounds__(256) void k_bsort(const unsigned* __restrict__ ebuf, const int* __restrict__ rowptr,
    int* __restrict__ colv, int n)
{
  __shared__ int cl[128];
  __shared__ int sc2[256];
  __shared__ unsigned stg[STCAP];

  const int t = threadIdx.x;
  const int b = blockIdx.x;
  const int r0 = b << 7;
  const int beg = rowptr[r0];
  const int rend = (r0 + 128 < n) ? (r0 + 128) : n;
  const int end = rowptr[rend];
  const int total = end - beg;

  if (t < 128) cl[t] = 0;
  __syncthreads();
  for (int i = beg + t; i < end; i += 256) atomicAdd(&cl[ebuf[i] & 127u], 1);
  __syncthreads();

  int v = (t < 128) ? cl[t] : 0;
  sc2[t] = v; __syncthreads();
  for (int off = 1; off < 256; off <<= 1){
    int u = (t >= off) ? sc2[t - off] : 0;
    __syncthreads();
    sc2[t] += u;
    __syncthreads();
  }
  if (t < 128) cl[t] = sc2[t] - v;   // exclusive prefix = running position
  __syncthreads();

  if (total <= STCAP){
    for (int i = beg + t; i < end; i += 256){
      unsigned u = ebuf[i];
      int p = atomicAdd(&cl[u & 127u], 1);
      stg[p] = u >> 7;
    }
    __syncthreads();
    for (int i = t; i < total; i += 256) colv[beg + i] = (int)stg[i];
  } else {
    for (int i = beg + t; i < end; i += 256){
      unsigned u = ebuf[i];
      int p = atomicAdd(&cl[u & 127u], 1);
      colv[beg + p] = (int)(u >> 7);
    }
  }
}

// ---------------- GEMM: G[i,:] = bf16( dinv[i] * (A[i,:] @ W) ) ----------------

__global__ __launch_bounds__(512) void k_gemm(const float* __restrict__ A, const float* __restrict__ W,
    const float* __restrict__ dinv, unsigned short* __restrict__ G, int n)
{
  __shared__ float Ws[128 * 128];
  __shared__ float As[128 * 132];
  const int t = threadIdx.x;
  const int rowBase = blockIdx.x * 128;
  {
    const float4* Wv = (const float4*)W;
    float4* Wsv = (float4*)Ws;
    #pragma unroll
    for (int j = 0; j < 8; j++) Wsv[t + j * 512] = Wv[t + j * 512];
  }
  {
    #pragma unroll
    for (int j = 0; j < 8; j++){
      int id = t + j * 512;
      int r = id >> 5, c4 = id & 31;
      int gr = rowBase + r;
      float4 v = make_float4(0.f, 0.f, 0.f, 0.f);
      if (gr < n) v = *(const float4*)(A + (size_t)gr * 128 + c4 * 4);
      *(float4*)(&As[r * 132 + c4 * 4]) = v;
    }
  }
  __syncthreads();

  const int ci = t & 15;
  const int r0 = (t >> 4) * 4;
  float acc[4][8];
  #pragma unroll
  for (int i = 0; i < 4; i++)
    #pragma unroll
    for (int j = 0; j < 8; j++) acc[i][j] = 0.f;

  const float* WsC = Ws + ci * 8;
  #pragma unroll 4
  for (int k = 0; k < 128; k++){
    float4 wa = *(const float4*)(WsC + k * 128);
    float4 wb = *(const float4*)(WsC + k * 128 + 4);
    float a0 = As[(r0    ) * 132 + k];
    float a1 = As[(r0 + 1) * 132 + k];
    float a2 = As[(r0 + 2) * 132 + k];
    float a3 = As[(r0 + 3) * 132 + k];
    float wv[8] = {wa.x, wa.y, wa.z, wa.w, wb.x, wb.y, wb.z, wb.w};
    float av[4] = {a0, a1, a2, a3};
    #pragma unroll
    for (int i = 0; i < 4; i++)
      #pragma unroll
      for (int j = 0; j < 8; j++)
        acc[i][j] = fmaf(av[i], wv[j], acc[i][j]);
  }

  #pragma unroll
  for (int i = 0; i < 4; i++){
    int gr = rowBase + r0 + i;
    if (gr >= n) continue;
    float dv = dinv[gr];
    short8 o;
    #pragma unroll
    for (int j = 0; j < 8; j++) o[j] = (short)f2bf(dv * acc[i][j]);
    *reinterpret_cast<short8*>(G + (size_t)gr * 128 + ci * 8) = o;
  }
}

// ---------------- SpMM ----------------

__global__ __launch_bounds__(256) void k_spmm(const unsigned* __restrict__ G, const int* __restrict__ rowptr,
    const int* __restrict__ colv, const float* __restrict__ dinv, const float* __restrict__ bias,
    float* __restrict__ H, int n)
{
  int wid  = (blockIdx.x * 256 + threadIdx.x) >> 6;
  int lane = threadIdx.x & 63;
  if (wid >= n) return;
  unsigned u = G[(size_t)wid * 64 + lane];          // self loop
  float acc0 = bflo(u), acc1 = bfhi(u);
  int e = rowptr[wid], e1 = rowptr[wid + 1];
  for (; e + 4 <= e1; e += 4){
    int s0 = colv[e], s1 = colv[e + 1], s2 = colv[e + 2], s3 = colv[e + 3];
    unsigned a = G[(size_t)s0 * 64 + lane];
    unsigned b = G[(size_t)s1 * 64 + lane];
    unsigned c = G[(size_t)s2 * 64 + lane];
    unsigned d = G[(size_t)s3 * 64 + lane];
    acc0 += bflo(a) + bflo(b) + bflo(c) + bflo(d);
    acc1 += bfhi(a) + bfhi(b) + bfhi(c) + bfhi(d);
  }
  for (; e < e1; ++e){
    unsigned a = G[(size_t)colv[e] * 64 + lane];
    acc0 += bflo(a); acc1 += bfhi(a);
  }
  float dv = dinv[wid];
  float r0 = fmaxf(fmaf(dv, acc0, bias[lane * 2    ]), 0.f);
  float r1 = fmaxf(fmaf(dv, acc1, bias[lane * 2 + 1]), 0.f);
  *reinterpret_cast<float2*>(H + (size_t)wid * 128 + lane * 2) = make_float2(r0, r1);
}

// ---------------- layer 3 ----------------

__global__ __launch_bounds__(256) void k_gemv3(const float* __restrict__ H, const float* __restrict__ W3,
    const float* __restrict__ dinv, float* __restrict__ tvec, float* __restrict__ aggv, int n)
{
  int wid  = (blockIdx.x * 256 + threadIdx.x) >> 6;
  int lane = threadIdx.x & 63;
  if (wid >= n) return;
  float2 h = *(const float2*)(H + (size_t)wid * 128 + lane * 2);
  float2 w = *(const float2*)(W3 + lane * 2);
  float v = h.x * w.x + h.y * w.y;
  #pragma unroll
  for (int off = 32; off; off >>= 1) v += __shfl_xor(v, off);
  if (lane == 0){
    float tv = dinv[wid] * v;
    tvec[wid] = tv;
    aggv[wid] = tv;
  }
}

__global__ __launch_bounds__(256) void k_edge3(const int* __restrict__ src, const int* __restrict__ dst,
    const float* __restrict__ tvec, float* __restrict__ aggv, int E)
{
  int e = blockIdx.x * 256 + threadIdx.x;
  if (e < E) atomicAdd(&aggv[dst[e]], tvec[src[e]]);
}

__global__ __launch_bounds__(256) void k_final(const float* __restrict__ aggv, const float* __restrict__ dinv,
    const float* __restrict__ b3, const float* __restrict__ x, float* __restrict__ out, int n)
{
  int i = blockIdx.x * 256 + threadIdx.x;
  if (i >= n) return;
  float v = fmaxf(fmaf(dinv[i], aggv[i], b3[0]), 0.f);
  out[i] = v + x[(size_t)i * 128 + 127];
}

// ---------------- launch ----------------

extern "C" void kernel_launch(void* const* d_in, const int* in_sizes, int n_in,
                              void* d_out, int out_size, void* d_ws, size_t ws_size,
                              hipStream_t stream)
{
  const float* x  = (const float*)d_in[0];
  const int*   ei = (const int*)d_in[1];
  const float* W1 = (const float*)d_in[3];
  const float* b1 = (const float*)d_in[4];
  const float* W2 = (const float*)d_in[5];
  const float* b2 = (const float*)d_in[6];
  const float* W3 = (const float*)d_in[7];
  const float* b3 = (const float*)d_in[8];
  float* out = (float*)d_out;

  const int N = in_sizes[0] / 128;
  const int E = in_sizes[1] / 2;
  const int* src = ei;
  const int* dst = ei + E;
  const int NB = (N + 127) >> 7;     // 128-row buckets

  char* wsb = (char*)d_ws;
  size_t off = 0;
  auto carve = [&](size_t bytes) -> void* {
    void* p = wsb + off;
    off += bytes;
    off = (off + 255) & ~(size_t)255;
    return p;
  };
  float*    dinv   = (float*)carve((size_t)N * 4);
  int*      cnt    = (int*)carve((size_t)N * 4);
  int*      rowptr = (int*)carve((size_t)(N + 1) * 4);
  int*      colv   = (int*)carve((size_t)E * 4);
  int*      blk    = (int*)carve(4096);
  int*      bpos   = (int*)carve((size_t)NB * 4);
  float*    tvec   = (float*)carve((size_t)N * 4);
  float*    aggv   = (float*)carve((size_t)N * 4);
  unsigned* G      = (unsigned*)carve((size_t)N * 256);  // bf16 N x 128
  float*    H      = (float*)carve((size_t)N * 512);     // f32  N x 128
  unsigned* ebuf   = (unsigned*)H;                       // overlay: dead before spmm1 writes H

  const int nB = (N + 1023) / 1024;

  hipMemsetAsync(cnt, 0, (size_t)N * 4, stream);
  k_hist   <<<(E + 255) / 256, 256, 0, stream>>>(dst, cnt, E);
  k_dinv   <<<(N + 255) / 256, 256, 0, stream>>>(cnt, dinv, N);
  k_scan1  <<<nB, 256, 0, stream>>>(cnt, rowptr, blk, N);
  k_scan2  <<<1, 256, 0, stream>>>(blk, nB);
  k_scan3  <<<nB, 256, 0, stream>>>(rowptr, blk, N, E);
  k_binit  <<<(NB + 255) / 256, 256, 0, stream>>>(rowptr, bpos, NB);
  k_part   <<<(E + PART_C - 1) / PART_C, 1024, 0, stream>>>(src, dst, bpos, ebuf, E, NB);
  k_bsort  <<<NB, 256, 0, stream>>>(ebuf, rowptr, colv, N);

  // layer 1
  k_gemm<<<(N + 127) / 128, 512, 0, stream>>>(x, W1, dinv, (unsigned short*)G, N);
  k_spmm<<<(N + 3) / 4, 256, 0, stream>>>(G, rowptr, colv, dinv, b1, H, N);
  // layer 2
  k_gemm<<<(N + 127) / 128, 512, 0, stream>>>(H, W2, dinv, (unsigned short*)G, N);
  k_spmm<<<(N + 3) / 4, 256, 0, stream>>>(G, rowptr, colv, dinv, b2, H, N);
  // layer 3 (HID -> 1)
  k_gemv3<<<(N + 3) / 4, 256, 0, stream>>>(H, W3, dinv, tvec, aggv, N);
  k_edge3<<<(E + 255) / 256, 256, 0, stream>>>(src, dst, tvec, aggv, E);
  k_final<<<(N + 255) / 256, 256, 0, stream>>>(aggv, dinv, b3, x, out, N);
}

// Round 3
// 361.057 us; speedup vs baseline: 1.6094x; 1.3850x over previous
//
#include <hip/hip_runtime.h>
#include <hip/hip_bf16.h>

typedef __attribute__((ext_vector_type(8))) short short8;

static __device__ __forceinline__ float bflo(unsigned u){ return __uint_as_float(u << 16); }
static __device__ __forceinline__ float bfhi(unsigned u){ return __uint_as_float(u & 0xffff0000u); }
static __device__ __forceinline__ unsigned short f2bf(float f){
  unsigned u = __float_as_uint(f);
  unsigned r = u + 0x7fffu + ((u >> 16) & 1u);
  return (unsigned short)(r >> 16);
}

#define NBMAX  1024
#define PART_C 8192
#define STCAP  4096

// ---------------- bucket pipeline (replaces hist/scan/scatter) ----------------

// per-block LDS histogram of dst>>7 -> global bucket counts
__global__ __launch_bounds__(1024) void k_bcnt(const int* __restrict__ dst, int* __restrict__ bcnt,
                                               int E, int NB){
  __shared__ int h[NBMAX];
  const int t = threadIdx.x;
  for (int i = t; i < NB; i += 1024) h[i] = 0;
  __syncthreads();
  for (int e = blockIdx.x * 1024 + t; e < E; e += gridDim.x * 1024)
    atomicAdd(&h[dst[e] >> 7], 1);
  __syncthreads();
  for (int i = t; i < NB; i += 1024) if (h[i]) atomicAdd(&bcnt[i], h[i]);
}

// one-block exclusive scan of bucket counts -> bstart (stable) and bpos (reservation)
__global__ __launch_bounds__(1024) void k_bscan(const int* __restrict__ bcnt, int* __restrict__ bstart,
    int* __restrict__ bpos, int* __restrict__ rowptr, int NB, int N, int E){
  __shared__ int sc[1024];
  const int t = threadIdx.x;
  int v = (t < NB) ? bcnt[t] : 0;
  sc[t] = v; __syncthreads();
  for (int off = 1; off < 1024; off <<= 1){
    int u = (t >= off) ? sc[t - off] : 0;
    __syncthreads();
    sc[t] += u;
    __syncthreads();
  }
  int excl = sc[t] - v;
  if (t < NB){ bstart[t] = excl; bpos[t] = excl; }
  if (t == 0){ bstart[NB] = E; rowptr[N] = E; }
}

// partition pass: 8192 edges/block, bucket by dst>>7, LDS-staged coalesced writes
__global__ __launch_bounds__(1024) void k_part(const int* __restrict__ src, const int* __restrict__ dst,
    int* __restrict__ bpos, unsigned* __restrict__ ebuf, int E, int NB)
{
  __shared__ int hist[NBMAX + 1];
  __shared__ int hist2[NBMAX];
  __shared__ int gbase[NBMAX];
  __shared__ int sc[1024];
  __shared__ unsigned staged[PART_C];

  const int t = threadIdx.x;
  const int base = blockIdx.x * PART_C;

  for (int i = t; i < NBMAX; i += 1024){ hist[i] = 0; hist2[i] = 0; }
  __syncthreads();

  unsigned up[8];
  int bb[8];
  #pragma unroll
  for (int j = 0; j < 8; j++){
    int e = base + j * 1024 + t;
    if (e < E){
      int s = src[e], d = dst[e];
      bb[j] = d >> 7;
      up[j] = ((unsigned)s << 7) | (unsigned)(d & 127);
      atomicAdd(&hist[bb[j]], 1);
    } else bb[j] = -1;
  }
  __syncthreads();

  int v = (t < NB) ? hist[t] : 0;
  sc[t] = v; __syncthreads();
  for (int off = 1; off < 1024; off <<= 1){
    int u = (t >= off) ? sc[t - off] : 0;
    __syncthreads();
    sc[t] += u;
    __syncthreads();
  }
  int incl = sc[t];
  if (t < NB) hist[t] = incl - v;
  if (t == NB - 1) hist[NB] = incl;
  if (t < NB && v > 0) gbase[t] = atomicAdd(&bpos[t], v);
  __syncthreads();

  #pragma unroll
  for (int j = 0; j < 8; j++){
    if (bb[j] >= 0){
      int r = atomicAdd(&hist2[bb[j]], 1);
      staged[hist[bb[j]] + r] = up[j];
    }
  }
  __syncthreads();

  int total = hist[NB];
  for (int i = t; i < total; i += 1024){
    int lo = 0, hi = NB;
    while (hi - lo > 1){
      int mid = (lo + hi) >> 1;
      if (hist[mid] <= i) lo = mid; else hi = mid;
    }
    ebuf[gbase[lo] + (i - hist[lo])] = staged[i];
  }
}

// fine sort within each 128-row bucket; also emits rowptr + dinv
__global__ __launch_bounds__(256) void k_bsort(const unsigned* __restrict__ ebuf, const int* __restrict__ bstart,
    int* __restrict__ rowptr, int* __restrict__ colv, float* __restrict__ dinv, int n)
{
  __shared__ int cl[128];
  __shared__ int sc2[256];
  __shared__ unsigned stg[STCAP];

  const int t = threadIdx.x;
  const int b = blockIdx.x;
  const int r0 = b << 7;
  const int beg = bstart[b];
  const int end = bstart[b + 1];
  const int total = end - beg;

  if (t < 128) cl[t] = 0;
  __syncthreads();
  for (int i = beg + t; i < end; i += 256) atomicAdd(&cl[ebuf[i] & 127u], 1);
  __syncthreads();

  int v = (t < 128) ? cl[t] : 0;
  sc2[t] = v; __syncthreads();
  for (int off = 1; off < 256; off <<= 1){
    int u = (t >= off) ? sc2[t - off] : 0;
    __syncthreads();
    sc2[t] += u;
    __syncthreads();
  }
  int excl = sc2[t] - v;
  if (t < 128){
    int node = r0 + t;
    if (node < n){
      rowptr[node] = beg + excl;
      dinv[node]   = rsqrtf((float)(v + 1));   // +1 self loop
    }
    cl[t] = excl;   // running position for sort
  }
  __syncthreads();

  if (total <= STCAP){
    for (int i = beg + t; i < end; i += 256){
      unsigned u = ebuf[i];
      int p = atomicAdd(&cl[u & 127u], 1);
      stg[p] = u >> 7;
    }
    __syncthreads();
    for (int i = t; i < total; i += 256) colv[beg + i] = (int)stg[i];
  } else {
    for (int i = beg + t; i < end; i += 256){
      unsigned u = ebuf[i];
      int p = atomicAdd(&cl[u & 127u], 1);
      colv[beg + p] = (int)(u >> 7);
    }
  }
}

// ---------------- GEMM: G[i,:] = bf16( dinv[i] * (A[i,:] @ W) ) ----------------

__global__ __launch_bounds__(512) void k_gemm(const float* __restrict__ A, const float* __restrict__ W,
    const float* __restrict__ dinv, unsigned short* __restrict__ G, int n)
{
  __shared__ float Ws[128 * 128];
  __shared__ float As[128 * 132];
  const int t = threadIdx.x;
  const int rowBase = blockIdx.x * 128;
  {
    const float4* Wv = (const float4*)W;
    float4* Wsv = (float4*)Ws;
    #pragma unroll
    for (int j = 0; j < 8; j++) Wsv[t + j * 512] = Wv[t + j * 512];
  }
  {
    #pragma unroll
    for (int j = 0; j < 8; j++){
      int id = t + j * 512;
      int r = id >> 5, c4 = id & 31;
      int gr = rowBase + r;
      float4 v = make_float4(0.f, 0.f, 0.f, 0.f);
      if (gr < n) v = *(const float4*)(A + (size_t)gr * 128 + c4 * 4);
      *(float4*)(&As[r * 132 + c4 * 4]) = v;
    }
  }
  __syncthreads();

  const int ci = t & 15;
  const int r0 = (t >> 4) * 4;
  float acc[4][8];
  #pragma unroll
  for (int i = 0; i < 4; i++)
    #pragma unroll
    for (int j = 0; j < 8; j++) acc[i][j] = 0.f;

  const float* WsC = Ws + ci * 8;
  #pragma unroll 4
  for (int k = 0; k < 128; k++){
    float4 wa = *(const float4*)(WsC + k * 128);
    float4 wb = *(const float4*)(WsC + k * 128 + 4);
    float a0 = As[(r0    ) * 132 + k];
    float a1 = As[(r0 + 1) * 132 + k];
    float a2 = As[(r0 + 2) * 132 + k];
    float a3 = As[(r0 + 3) * 132 + k];
    float wv[8] = {wa.x, wa.y, wa.z, wa.w, wb.x, wb.y, wb.z, wb.w};
    float av[4] = {a0, a1, a2, a3};
    #pragma unroll
    for (int i = 0; i < 4; i++)
      #pragma unroll
      for (int j = 0; j < 8; j++)
        acc[i][j] = fmaf(av[i], wv[j], acc[i][j]);
  }

  #pragma unroll
  for (int i = 0; i < 4; i++){
    int gr = rowBase + r0 + i;
    if (gr >= n) continue;
    float dv = dinv[gr];
    short8 o;
    #pragma unroll
    for (int j = 0; j < 8; j++) o[j] = (short)f2bf(dv * acc[i][j]);
    *reinterpret_cast<short8*>(G + (size_t)gr * 128 + ci * 8) = o;
  }
}

// ---------------- SpMM ----------------

__global__ __launch_bounds__(256) void k_spmm(const unsigned* __restrict__ G, const int* __restrict__ rowptr,
    const int* __restrict__ colv, const float* __restrict__ dinv, const float* __restrict__ bias,
    float* __restrict__ H, int n)
{
  int wid  = (blockIdx.x * 256 + threadIdx.x) >> 6;
  int lane = threadIdx.x & 63;
  if (wid >= n) return;
  unsigned u = G[(size_t)wid * 64 + lane];          // self loop
  float acc0 = bflo(u), acc1 = bfhi(u);
  int e = rowptr[wid], e1 = rowptr[wid + 1];
  for (; e + 4 <= e1; e += 4){
    int s0 = colv[e], s1 = colv[e + 1], s2 = colv[e + 2], s3 = colv[e + 3];
    unsigned a = G[(size_t)s0 * 64 + lane];
    unsigned b = G[(size_t)s1 * 64 + lane];
    unsigned c = G[(size_t)s2 * 64 + lane];
    unsigned d = G[(size_t)s3 * 64 + lane];
    acc0 += bflo(a) + bflo(b) + bflo(c) + bflo(d);
    acc1 += bfhi(a) + bfhi(b) + bfhi(c) + bfhi(d);
  }
  for (; e < e1; ++e){
    unsigned a = G[(size_t)colv[e] * 64 + lane];
    acc0 += bflo(a); acc1 += bfhi(a);
  }
  float dv = dinv[wid];
  float r0 = fmaxf(fmaf(dv, acc0, bias[lane * 2    ]), 0.f);
  float r1 = fmaxf(fmaf(dv, acc1, bias[lane * 2 + 1]), 0.f);
  *reinterpret_cast<float2*>(H + (size_t)wid * 128 + lane * 2) = make_float2(r0, r1);
}

// ---------------- layer 3 ----------------

__global__ __launch_bounds__(256) void k_gemv3(const float* __restrict__ H, const float* __restrict__ W3,
    const float* __restrict__ dinv, float* __restrict__ tvec, int n)
{
  int wid  = (blockIdx.x * 256 + threadIdx.x) >> 6;
  int lane = threadIdx.x & 63;
  if (wid >= n) return;
  float2 h = *(const float2*)(H + (size_t)wid * 128 + lane * 2);
  float2 w = *(const float2*)(W3 + lane * 2);
  float v = h.x * w.x + h.y * w.y;
  #pragma unroll
  for (int off = 32; off; off >>= 1) v += __shfl_xor(v, off);
  if (lane == 0) tvec[wid] = dinv[wid] * v;
}

// CSR gather-sum over tvec (L2-resident), fused bias/relu/residual
__global__ __launch_bounds__(256) void k_final3(const float* __restrict__ tvec, const int* __restrict__ rowptr,
    const int* __restrict__ colv, const float* __restrict__ dinv, const float* __restrict__ b3,
    const float* __restrict__ x, float* __restrict__ out, int n)
{
  int i = blockIdx.x * 256 + threadIdx.x;
  if (i >= n) return;
  float s = tvec[i];                       // self loop
  int e = rowptr[i], e1 = rowptr[i + 1];
  for (; e < e1; ++e) s += tvec[colv[e]];
  float v = fmaxf(fmaf(dinv[i], s, b3[0]), 0.f);
  out[i] = v + x[(size_t)i * 128 + 127];   // residual: x[:, -1]
}

// ---------------- launch ----------------

extern "C" void kernel_launch(void* const* d_in, const int* in_sizes, int n_in,
                              void* d_out, int out_size, void* d_ws, size_t ws_size,
                              hipStream_t stream)
{
  const float* x  = (const float*)d_in[0];
  const int*   ei = (const int*)d_in[1];
  const float* W1 = (const float*)d_in[3];
  const float* b1 = (const float*)d_in[4];
  const float* W2 = (const float*)d_in[5];
  const float* b2 = (const float*)d_in[6];
  const float* W3 = (const float*)d_in[7];
  const float* b3 = (const float*)d_in[8];
  float* out = (float*)d_out;

  const int N = in_sizes[0] / 128;
  const int E = in_sizes[1] / 2;
  const int* src = ei;
  const int* dst = ei + E;
  const int NB = (N + 127) >> 7;

  char* wsb = (char*)d_ws;
  size_t off = 0;
  auto carve = [&](size_t bytes) -> void* {
    void* p = wsb + off;
    off += bytes;
    off = (off + 255) & ~(size_t)255;
    return p;
  };
  float*    dinv   = (float*)carve((size_t)N * 4);
  int*      rowptr = (int*)carve((size_t)(N + 1) * 4);
  int*      colv   = (int*)carve((size_t)E * 4);
  int*      bcnt   = (int*)carve((size_t)NB * 4);
  int*      bstart = (int*)carve((size_t)(NB + 1) * 4);
  int*      bpos   = (int*)carve((size_t)NB * 4);
  float*    tvec   = (float*)carve((size_t)N * 4);
  unsigned* G      = (unsigned*)carve((size_t)N * 256);  // bf16 N x 128
  float*    H      = (float*)carve((size_t)N * 512);     // f32  N x 128
  unsigned* ebuf   = (unsigned*)H;                       // overlay: dead before spmm1 writes H

  hipMemsetAsync(bcnt, 0, (size_t)NB * 4, stream);
  k_bcnt  <<<128, 1024, 0, stream>>>(dst, bcnt, E, NB);
  k_bscan <<<1, 1024, 0, stream>>>(bcnt, bstart, bpos, rowptr, NB, N, E);
  k_part  <<<(E + PART_C - 1) / PART_C, 1024, 0, stream>>>(src, dst, bpos, ebuf, E, NB);
  k_bsort <<<NB, 256, 0, stream>>>(ebuf, bstart, rowptr, colv, dinv, N);

  // layer 1
  k_gemm<<<(N + 127) / 128, 512, 0, stream>>>(x, W1, dinv, (unsigned short*)G, N);
  k_spmm<<<(N + 3) / 4, 256, 0, stream>>>(G, rowptr, colv, dinv, b1, H, N);
  // layer 2
  k_gemm<<<(N + 127) / 128, 512, 0, stream>>>(H, W2, dinv, (unsigned short*)G, N);
  k_spmm<<<(N + 3) / 4, 256, 0, stream>>>(G, rowptr, colv, dinv, b2, H, N);
  // layer 3 (HID -> 1)
  k_gemv3 <<<(N + 3) / 4, 256, 0, stream>>>(H, W3, dinv, tvec, N);
  k_final3<<<(N + 255) / 256, 256, 0, stream>>>(tvec, rowptr, colv, dinv, b3, x, out, N);
}

// Round 4
// 257.515 us; speedup vs baseline: 2.2566x; 1.4021x over previous
//
#include <hip/hip_runtime.h>
#include <hip/hip_bf16.h>

typedef __attribute__((ext_vector_type(8))) short short8;
typedef __attribute__((ext_vector_type(8))) __bf16 bf16x8;
typedef __attribute__((ext_vector_type(4))) float f32x4;

static __device__ __forceinline__ float bflo(unsigned u){ return __uint_as_float(u << 16); }
static __device__ __forceinline__ float bfhi(unsigned u){ return __uint_as_float(u & 0xffff0000u); }
static __device__ __forceinline__ unsigned short f2bf(float f){
  unsigned u = __float_as_uint(f);
  unsigned r = u + 0x7fffu + ((u >> 16) & 1u);
  return (unsigned short)(r >> 16);
}

#define NBMAX  1024
#define PART_C 8192
#define STCAP  4096

// ---------------- bucket pipeline ----------------

__global__ __launch_bounds__(1024) void k_bcnt(const int* __restrict__ dst, int* __restrict__ bcnt,
                                               int E, int NB){
  __shared__ int h[NBMAX];
  const int t = threadIdx.x;
  for (int i = t; i < NB; i += 1024) h[i] = 0;
  __syncthreads();
  for (int e = blockIdx.x * 1024 + t; e < E; e += gridDim.x * 1024)
    atomicAdd(&h[dst[e] >> 7], 1);
  __syncthreads();
  for (int i = t; i < NB; i += 1024) if (h[i]) atomicAdd(&bcnt[i], h[i]);
}

__global__ __launch_bounds__(1024) void k_bscan(const int* __restrict__ bcnt, int* __restrict__ bstart,
    int* __restrict__ bpos, int* __restrict__ rowptr, int NB, int N, int E){
  __shared__ int sc[1024];
  const int t = threadIdx.x;
  int v = (t < NB) ? bcnt[t] : 0;
  sc[t] = v; __syncthreads();
  for (int off = 1; off < 1024; off <<= 1){
    int u = (t >= off) ? sc[t - off] : 0;
    __syncthreads();
    sc[t] += u;
    __syncthreads();
  }
  int excl = sc[t] - v;
  if (t < NB){ bstart[t] = excl; bpos[t] = excl; }
  if (t == 0){ bstart[NB] = E; rowptr[N] = E; }
}

__global__ __launch_bounds__(1024) void k_part(const int* __restrict__ src, const int* __restrict__ dst,
    int* __restrict__ bpos, unsigned* __restrict__ ebuf, int E, int NB)
{
  __shared__ int hist[NBMAX + 1];
  __shared__ int hist2[NBMAX];
  __shared__ int gbase[NBMAX];
  __shared__ int sc[1024];
  __shared__ unsigned staged[PART_C];

  const int t = threadIdx.x;
  const int base = blockIdx.x * PART_C;

  for (int i = t; i < NBMAX; i += 1024){ hist[i] = 0; hist2[i] = 0; }
  __syncthreads();

  unsigned up[8];
  int bb[8];
  #pragma unroll
  for (int j = 0; j < 8; j++){
    int e = base + j * 1024 + t;
    if (e < E){
      int s = src[e], d = dst[e];
      bb[j] = d >> 7;
      up[j] = ((unsigned)s << 7) | (unsigned)(d & 127);
      atomicAdd(&hist[bb[j]], 1);
    } else bb[j] = -1;
  }
  __syncthreads();

  int v = (t < NB) ? hist[t] : 0;
  sc[t] = v; __syncthreads();
  for (int off = 1; off < 1024; off <<= 1){
    int u = (t >= off) ? sc[t - off] : 0;
    __syncthreads();
    sc[t] += u;
    __syncthreads();
  }
  int incl = sc[t];
  if (t < NB) hist[t] = incl - v;
  if (t == NB - 1) hist[NB] = incl;
  if (t < NB && v > 0) gbase[t] = atomicAdd(&bpos[t], v);
  __syncthreads();

  #pragma unroll
  for (int j = 0; j < 8; j++){
    if (bb[j] >= 0){
      int r = atomicAdd(&hist2[bb[j]], 1);
      staged[hist[bb[j]] + r] = up[j];
    }
  }
  __syncthreads();

  int total = hist[NB];
  for (int i = t; i < total; i += 1024){
    int lo = 0, hi = NB;
    while (hi - lo > 1){
      int mid = (lo + hi) >> 1;
      if (hist[mid] <= i) lo = mid; else hi = mid;
    }
    ebuf[gbase[lo] + (i - hist[lo])] = staged[i];
  }
}

__global__ __launch_bounds__(256) void k_bsort(const unsigned* __restrict__ ebuf, const int* __restrict__ bstart,
    int* __restrict__ rowptr, int* __restrict__ colv, float* __restrict__ dinv, int n)
{
  __shared__ int cl[128];
  __shared__ int sc2[256];
  __shared__ unsigned stg[STCAP];

  const int t = threadIdx.x;
  const int b = blockIdx.x;
  const int r0 = b << 7;
  const int beg = bstart[b];
  const int end = bstart[b + 1];
  const int total = end - beg;

  if (t < 128) cl[t] = 0;
  __syncthreads();
  for (int i = beg + t; i < end; i += 256) atomicAdd(&cl[ebuf[i] & 127u], 1);
  __syncthreads();

  int v = (t < 128) ? cl[t] : 0;
  sc2[t] = v; __syncthreads();
  for (int off = 1; off < 256; off <<= 1){
    int u = (t >= off) ? sc2[t - off] : 0;
    __syncthreads();
    sc2[t] += u;
    __syncthreads();
  }
  int excl = sc2[t] - v;
  if (t < 128){
    int node = r0 + t;
    if (node < n){
      rowptr[node] = beg + excl;
      dinv[node]   = rsqrtf((float)(v + 1));
    }
    cl[t] = excl;
  }
  __syncthreads();

  if (total <= STCAP){
    for (int i = beg + t; i < end; i += 256){
      unsigned u = ebuf[i];
      int p = atomicAdd(&cl[u & 127u], 1);
      stg[p] = u >> 7;
    }
    __syncthreads();
    for (int i = t; i < total; i += 256) colv[beg + i] = (int)stg[i];
  } else {
    for (int i = beg + t; i < end; i += 256){
      unsigned u = ebuf[i];
      int p = atomicAdd(&cl[u & 127u], 1);
      colv[beg + p] = (int)(u >> 7);
    }
  }
}

// ---------------- MFMA GEMM: G[i,:] = bf16( dinv[i] * (A[i,:] @ W) ) ----------------
// 512 threads = 8 waves; 128x128 tile, K=128; wave w owns cols w*16..w*16+15.
// A staged in LDS as bf16, XOR-swizzled 16B granules (g ^= row&7) -> conflict-free ds_read_b128.
// W read directly from global (64KB, L2-resident) into B fragments.
// Epilogue bounces through LDS (stride 136 shorts) for coalesced short8 stores.

template<bool AF32>
__global__ __launch_bounds__(512) void k_gemm_mfma(const void* __restrict__ Ain, const float* __restrict__ W,
    const float* __restrict__ dinv, unsigned short* __restrict__ G, int n)
{
  __shared__ unsigned short At[128 * 136];   // staging uses [128][128] swizzled; epilogue uses stride 136
  __shared__ float dl[128];

  const int t = threadIdx.x;
  const int rowBase = blockIdx.x * 128;
  const int w  = t >> 6;
  const int l  = t & 63;
  const int ln = l & 15;
  const int lg = l >> 4;

  if (t < 128){
    int gr = rowBase + t;
    dl[t] = (gr < n) ? dinv[gr] : 0.f;
  }

  // ---- stage A tile as bf16, swizzled ----
  #pragma unroll
  for (int i = 0; i < 4; i++){
    int flat = i * 4096 + t * 8;     // element index in 128x128 tile
    int r = flat >> 7, c = flat & 127;
    int gr = rowBase + r;
    unsigned short tmp[8];
    if constexpr (AF32){
      const float* A = (const float*)Ain;
      float4 v0 = make_float4(0.f,0.f,0.f,0.f), v1 = v0;
      if (gr < n){
        v0 = *(const float4*)(A + (size_t)gr * 128 + c);
        v1 = *(const float4*)(A + (size_t)gr * 128 + c + 4);
      }
      tmp[0]=f2bf(v0.x); tmp[1]=f2bf(v0.y); tmp[2]=f2bf(v0.z); tmp[3]=f2bf(v0.w);
      tmp[4]=f2bf(v1.x); tmp[5]=f2bf(v1.y); tmp[6]=f2bf(v1.z); tmp[7]=f2bf(v1.w);
    } else {
      const unsigned short* A = (const unsigned short*)Ain;
      short8 v = {};
      if (gr < n) v = *(const short8*)(A + (size_t)gr * 128 + c);
      *(short8*)tmp = v;
    }
    int g = (c >> 3) ^ (r & 7);
    *(short8*)((char*)At + r * 256 + g * 16) = *(const short8*)tmp;
  }

  // ---- B fragments from global W (bf16 on the fly) ----
  bf16x8 bfr[4];
  #pragma unroll
  for (int kk = 0; kk < 4; kk++){
    short8 tmp;
    #pragma unroll
    for (int j = 0; j < 8; j++){
      float wv = W[(kk * 32 + lg * 8 + j) * 128 + (w * 16 + ln)];
      tmp[j] = (short)f2bf(wv);
    }
    bfr[kk] = __builtin_bit_cast(bf16x8, tmp);
  }

  f32x4 acc[8];
  #pragma unroll
  for (int m = 0; m < 8; m++) acc[m] = (f32x4){0.f,0.f,0.f,0.f};

  __syncthreads();

  #pragma unroll
  for (int m = 0; m < 8; m++){
    int row = m * 16 + ln;
    #pragma unroll
    for (int kk = 0; kk < 4; kk++){
      int g = (kk * 4 + lg) ^ (row & 7);
      short8 av = *(const short8*)((const char*)At + row * 256 + g * 16);
      acc[m] = __builtin_amdgcn_mfma_f32_16x16x32_bf16(
          __builtin_bit_cast(bf16x8, av), bfr[kk], acc[m], 0, 0, 0);
    }
  }

  __syncthreads();   // all At reads done; reuse as epilogue buffer (stride 136)

  #pragma unroll
  for (int m = 0; m < 8; m++){
    #pragma unroll
    for (int r = 0; r < 4; r++){
      int row = m * 16 + lg * 4 + r;
      At[row * 136 + w * 16 + ln] = f2bf(dl[row] * acc[m][r]);
    }
  }
  __syncthreads();

  #pragma unroll
  for (int i = 0; i < 4; i++){
    int flat = i * 4096 + t * 8;
    int r = flat >> 7, c = flat & 127;
    int gr = rowBase + r;
    if (gr < n)
      *(short8*)(G + (size_t)gr * 128 + c) = *(const short8*)(At + r * 136 + c);
  }
}

// ---------------- SpMM: H = bf16( relu( dinv*(gather-sum) + b ) ) ----------------

__global__ __launch_bounds__(256) void k_spmm(const unsigned* __restrict__ G, const int* __restrict__ rowptr,
    const int* __restrict__ colv, const float* __restrict__ dinv, const float* __restrict__ bias,
    unsigned* __restrict__ H, int n)
{
  int wid  = (blockIdx.x * 256 + threadIdx.x) >> 6;
  int lane = threadIdx.x & 63;
  if (wid >= n) return;
  unsigned u = G[(size_t)wid * 64 + lane];          // self loop
  float acc0 = bflo(u), acc1 = bfhi(u);
  int e = rowptr[wid], e1 = rowptr[wid + 1];
  for (; e + 4 <= e1; e += 4){
    int s0 = colv[e], s1 = colv[e + 1], s2 = colv[e + 2], s3 = colv[e + 3];
    unsigned a = G[(size_t)s0 * 64 + lane];
    unsigned b = G[(size_t)s1 * 64 + lane];
    unsigned c = G[(size_t)s2 * 64 + lane];
    unsigned d = G[(size_t)s3 * 64 + lane];
    acc0 += bflo(a) + bflo(b) + bflo(c) + bflo(d);
    acc1 += bfhi(a) + bfhi(b) + bfhi(c) + bfhi(d);
  }
  for (; e < e1; ++e){
    unsigned a = G[(size_t)colv[e] * 64 + lane];
    acc0 += bflo(a); acc1 += bfhi(a);
  }
  float dv = dinv[wid];
  float r0 = fmaxf(fmaf(dv, acc0, bias[lane * 2    ]), 0.f);
  float r1 = fmaxf(fmaf(dv, acc1, bias[lane * 2 + 1]), 0.f);
  H[(size_t)wid * 64 + lane] = (unsigned)f2bf(r0) | ((unsigned)f2bf(r1) << 16);
}

// ---------------- layer 3 ----------------

__global__ __launch_bounds__(256) void k_gemv3(const unsigned* __restrict__ H, const float* __restrict__ W3,
    const float* __restrict__ dinv, float* __restrict__ tvec, int n)
{
  int wid  = (blockIdx.x * 256 + threadIdx.x) >> 6;
  int lane = threadIdx.x & 63;
  if (wid >= n) return;
  unsigned u = H[(size_t)wid * 64 + lane];
  float2 wv = *(const float2*)(W3 + lane * 2);
  float v = bflo(u) * wv.x + bfhi(u) * wv.y;
  #pragma unroll
  for (int off = 32; off; off >>= 1) v += __shfl_xor(v, off);
  if (lane == 0) tvec[wid] = dinv[wid] * v;
}

__global__ __launch_bounds__(256) void k_final3(const float* __restrict__ tvec, const int* __restrict__ rowptr,
    const int* __restrict__ colv, const float* __restrict__ dinv, const float* __restrict__ b3,
    const float* __restrict__ x, float* __restrict__ out, int n)
{
  int i = blockIdx.x * 256 + threadIdx.x;
  if (i >= n) return;
  float s = tvec[i];
  int e = rowptr[i], e1 = rowptr[i + 1];
  for (; e < e1; ++e) s += tvec[colv[e]];
  float v = fmaxf(fmaf(dinv[i], s, b3[0]), 0.f);
  out[i] = v + x[(size_t)i * 128 + 127];
}

// ---------------- launch ----------------

extern "C" void kernel_launch(void* const* d_in, const int* in_sizes, int n_in,
                              void* d_out, int out_size, void* d_ws, size_t ws_size,
                              hipStream_t stream)
{
  const float* x  = (const float*)d_in[0];
  const int*   ei = (const int*)d_in[1];
  const float* W1 = (const float*)d_in[3];
  const float* b1 = (const float*)d_in[4];
  const float* W2 = (const float*)d_in[5];
  const float* b2 = (const float*)d_in[6];
  const float* W3 = (const float*)d_in[7];
  const float* b3 = (const float*)d_in[8];
  float* out = (float*)d_out;

  const int N = in_sizes[0] / 128;
  const int E = in_sizes[1] / 2;
  const int* src = ei;
  const int* dst = ei + E;
  const int NB = (N + 127) >> 7;

  char* wsb = (char*)d_ws;
  size_t off = 0;
  auto carve = [&](size_t bytes) -> void* {
    void* p = wsb + off;
    off += bytes;
    off = (off + 255) & ~(size_t)255;
    return p;
  };
  float*    dinv   = (float*)carve((size_t)N * 4);
  int*      rowptr = (int*)carve((size_t)(N + 1) * 4);
  int*      colv   = (int*)carve((size_t)E * 4);
  int*      bcnt   = (int*)carve((size_t)NB * 4);
  int*      bstart = (int*)carve((size_t)(NB + 1) * 4);
  int*      bpos   = (int*)carve((size_t)NB * 4);
  float*    tvec   = (float*)carve((size_t)N * 4);
  unsigned* G      = (unsigned*)carve((size_t)N * 256);  // bf16 N x 128
  unsigned* H      = (unsigned*)carve((size_t)N * 256);  // bf16 N x 128
  unsigned* ebuf   = (unsigned*)H;                       // overlay: dead before spmm1 writes H

  hipMemsetAsync(bcnt, 0, (size_t)NB * 4, stream);
  k_bcnt  <<<128, 1024, 0, stream>>>(dst, bcnt, E, NB);
  k_bscan <<<1, 1024, 0, stream>>>(bcnt, bstart, bpos, rowptr, NB, N, E);
  k_part  <<<(E + PART_C - 1) / PART_C, 1024, 0, stream>>>(src, dst, bpos, ebuf, E, NB);
  k_bsort <<<NB, 256, 0, stream>>>(ebuf, bstart, rowptr, colv, dinv, N);

  // layer 1
  k_gemm_mfma<true ><<<(N + 127) / 128, 512, 0, stream>>>(x, W1, dinv, (unsigned short*)G, N);
  k_spmm<<<(N + 3) / 4, 256, 0, stream>>>(G, rowptr, colv, dinv, b1, H, N);
  // layer 2
  k_gemm_mfma<false><<<(N + 127) / 128, 512, 0, stream>>>(H, W2, dinv, (unsigned short*)G, N);
  k_spmm<<<(N + 3) / 4, 256, 0, stream>>>(G, rowptr, colv, dinv, b2, H, N);
  // layer 3 (HID -> 1)
  k_gemv3 <<<(N + 3) / 4, 256, 0, stream>>>(H, W3, dinv, tvec, N);
  k_final3<<<(N + 255) / 256, 256, 0, stream>>>(tvec, rowptr, colv, dinv, b3, x, out, N);
}

// Round 5
// 201.180 us; speedup vs baseline: 2.8884x; 1.2800x over previous
//
#include <hip/hip_runtime.h>
#include <hip/hip_bf16.h>

typedef __attribute__((ext_vector_type(8))) short short8;
typedef __attribute__((ext_vector_type(8))) __bf16 bf16x8;
typedef __attribute__((ext_vector_type(4))) float f32x4;

static __device__ __forceinline__ float bflo(unsigned u){ return __uint_as_float(u << 16); }
static __device__ __forceinline__ float bfhi(unsigned u){ return __uint_as_float(u & 0xffff0000u); }
static __device__ __forceinline__ unsigned short f2bf(float f){
  unsigned u = __float_as_uint(f);
  unsigned r = u + 0x7fffu + ((u >> 16) & 1u);
  return (unsigned short)(r >> 16);
}

// ---- fp8 e4m3 conversions (HW via builtins; self-consistent SW fallback) ----
#if __has_builtin(__builtin_amdgcn_cvt_pk_fp8_f32)
static __device__ __forceinline__ unsigned char f2e4m3(float f){
  return (unsigned char)(__builtin_amdgcn_cvt_pk_fp8_f32(f, 0.f, 0, false) & 0xff);
}
#else
static __device__ __forceinline__ unsigned char f2e4m3(float f){
  unsigned s = (__float_as_uint(f) >> 31) << 7;
  float a = fabsf(f);
  if (a >= 448.f) return (unsigned char)(s | 0x7e);
  if (a < 0.0009765625f) return (unsigned char)s;          // < 2^-10 -> 0
  if (a >= 0.015625f){                                      // normal
    int e; float m = frexpf(a, &e);                         // a = m*2^e, m in [.5,1)
    int q = (int)rintf(m * 16.f);
    int E = e - 1 + 7;
    if (q == 16){ q = 8; E++; }
    if (E >= 16) return (unsigned char)(s | 0x7e);
    return (unsigned char)(s | (E << 3) | (q - 8));
  } else {                                                  // subnormal
    int q = (int)rintf(a * 512.f);
    if (q > 7) return (unsigned char)(s | 0x08);
    return (unsigned char)(s | q);
  }
}
#endif

#if __has_builtin(__builtin_amdgcn_cvt_pk_f32_fp8)
static __device__ __forceinline__ float4 e4m3x4_to_f32(unsigned u){
  auto lo = __builtin_amdgcn_cvt_pk_f32_fp8((int)u, false);
  auto hi = __builtin_amdgcn_cvt_pk_f32_fp8((int)u, true);
  return make_float4(lo[0], lo[1], hi[0], hi[1]);
}
#else
static __device__ __forceinline__ float e4m3_1(unsigned b){
  unsigned s = b >> 7, e = (b >> 3) & 15, m = b & 7;
  float v = e ? ldexpf((float)(8 + m) * 0.125f, (int)e - 7) : ldexpf((float)m * 0.125f, -6);
  return s ? -v : v;
}
static __device__ __forceinline__ float4 e4m3x4_to_f32(unsigned u){
  return make_float4(e4m3_1(u & 255), e4m3_1((u >> 8) & 255), e4m3_1((u >> 16) & 255), e4m3_1(u >> 24));
}
#endif

#define NBMAX  1024
#define PART_C 8192
#define STCAP  4096

// ---------------- bucket pipeline ----------------

__global__ __launch_bounds__(1024) void k_bcnt(const int* __restrict__ dst, int* __restrict__ bcnt,
                                               int E, int NB){
  __shared__ int h[NBMAX];
  const int t = threadIdx.x;
  for (int i = t; i < NB; i += 1024) h[i] = 0;
  __syncthreads();
  for (int e = blockIdx.x * 1024 + t; e < E; e += gridDim.x * 1024)
    atomicAdd(&h[dst[e] >> 7], 1);
  __syncthreads();
  for (int i = t; i < NB; i += 1024) if (h[i]) atomicAdd(&bcnt[i], h[i]);
}

__global__ __launch_bounds__(1024) void k_bscan(const int* __restrict__ bcnt, int* __restrict__ bstart,
    int* __restrict__ bpos, int* __restrict__ rowptr, int NB, int N, int E){
  __shared__ int sc[1024];
  const int t = threadIdx.x;
  int v = (t < NB) ? bcnt[t] : 0;
  sc[t] = v; __syncthreads();
  for (int off = 1; off < 1024; off <<= 1){
    int u = (t >= off) ? sc[t - off] : 0;
    __syncthreads();
    sc[t] += u;
    __syncthreads();
  }
  int excl = sc[t] - v;
  if (t < NB){ bstart[t] = excl; bpos[t] = excl; }
  if (t == 0){ bstart[NB] = E; rowptr[N] = E; }
}

__global__ __launch_bounds__(1024) void k_part(const int* __restrict__ src, const int* __restrict__ dst,
    int* __restrict__ bpos, unsigned* __restrict__ ebuf, int E, int NB)
{
  __shared__ int hist[NBMAX + 1];
  __shared__ int hist2[NBMAX];
  __shared__ int gbase[NBMAX];
  __shared__ int sc[1024];
  __shared__ unsigned staged[PART_C];

  const int t = threadIdx.x;
  const int base = blockIdx.x * PART_C;

  for (int i = t; i < NBMAX; i += 1024){ hist[i] = 0; hist2[i] = 0; }
  __syncthreads();

  unsigned up[8];
  int bb[8];
  #pragma unroll
  for (int j = 0; j < 8; j++){
    int e = base + j * 1024 + t;
    if (e < E){
      int s = src[e], d = dst[e];
      bb[j] = d >> 7;
      up[j] = ((unsigned)s << 7) | (unsigned)(d & 127);
      atomicAdd(&hist[bb[j]], 1);
    } else bb[j] = -1;
  }
  __syncthreads();

  int v = (t < NB) ? hist[t] : 0;
  sc[t] = v; __syncthreads();
  for (int off = 1; off < 1024; off <<= 1){
    int u = (t >= off) ? sc[t - off] : 0;
    __syncthreads();
    sc[t] += u;
    __syncthreads();
  }
  int incl = sc[t];
  if (t < NB) hist[t] = incl - v;
  if (t == NB - 1) hist[NB] = incl;
  if (t < NB && v > 0) gbase[t] = atomicAdd(&bpos[t], v);
  __syncthreads();

  #pragma unroll
  for (int j = 0; j < 8; j++){
    if (bb[j] >= 0){
      int r = atomicAdd(&hist2[bb[j]], 1);
      staged[hist[bb[j]] + r] = up[j];
    }
  }
  __syncthreads();

  int total = hist[NB];
  for (int i = t; i < total; i += 1024){
    int lo = 0, hi = NB;
    while (hi - lo > 1){
      int mid = (lo + hi) >> 1;
      if (hist[mid] <= i) lo = mid; else hi = mid;
    }
    ebuf[gbase[lo] + (i - hist[lo])] = staged[i];
  }
}

__global__ __launch_bounds__(256) void k_bsort(const unsigned* __restrict__ ebuf, const int* __restrict__ bstart,
    int* __restrict__ rowptr, int* __restrict__ colv, float* __restrict__ dinv, int n)
{
  __shared__ int cl[128];
  __shared__ int sc2[256];
  __shared__ unsigned stg[STCAP];

  const int t = threadIdx.x;
  const int b = blockIdx.x;
  const int r0 = b << 7;
  const int beg = bstart[b];
  const int end = bstart[b + 1];
  const int total = end - beg;

  if (t < 128) cl[t] = 0;
  __syncthreads();
  for (int i = beg + t; i < end; i += 256) atomicAdd(&cl[ebuf[i] & 127u], 1);
  __syncthreads();

  int v = (t < 128) ? cl[t] : 0;
  sc2[t] = v; __syncthreads();
  for (int off = 1; off < 256; off <<= 1){
    int u = (t >= off) ? sc2[t - off] : 0;
    __syncthreads();
    sc2[t] += u;
    __syncthreads();
  }
  int excl = sc2[t] - v;
  if (t < 128){
    int node = r0 + t;
    if (node < n){
      rowptr[node] = beg + excl;
      dinv[node]   = rsqrtf((float)(v + 1));
    }
    cl[t] = excl;
  }
  __syncthreads();

  if (total <= STCAP){
    for (int i = beg + t; i < end; i += 256){
      unsigned u = ebuf[i];
      int p = atomicAdd(&cl[u & 127u], 1);
      stg[p] = u >> 7;
    }
    __syncthreads();
    for (int i = t; i < total; i += 256) colv[beg + i] = (int)stg[i];
  } else {
    for (int i = beg + t; i < end; i += 256){
      unsigned u = ebuf[i];
      int p = atomicAdd(&cl[u & 127u], 1);
      colv[beg + p] = (int)(u >> 7);
    }
  }
}

// ---------------- MFMA GEMM: G8[i,:] = fp8( dinv[i] * (A[i,:] @ W) ) ----------------
// 512 threads = 8 waves; 128x128 tile, K=128; wave w owns cols w*16..w*16+15.
// A staged in LDS as bf16, XOR-swizzled 16B granules; W from global (L2-resident).
// Epilogue: f32 -> fp8 e4m3, LDS byte-bounce (stride 136B) -> coalesced 32B stores.

template<bool AF32>
__global__ __launch_bounds__(512) void k_gemm_mfma(const void* __restrict__ Ain, const float* __restrict__ W,
    const float* __restrict__ dinv, unsigned char* __restrict__ G8, int n)
{
  __shared__ unsigned short At[128 * 136];
  __shared__ float dl[128];

  const int t = threadIdx.x;
  const int rowBase = blockIdx.x * 128;
  const int w  = t >> 6;
  const int l  = t & 63;
  const int ln = l & 15;
  const int lg = l >> 4;

  if (t < 128){
    int gr = rowBase + t;
    dl[t] = (gr < n) ? dinv[gr] : 0.f;
  }

  #pragma unroll
  for (int i = 0; i < 4; i++){
    int flat = i * 4096 + t * 8;
    int r = flat >> 7, c = flat & 127;
    int gr = rowBase + r;
    unsigned short tmp[8];
    if constexpr (AF32){
      const float* A = (const float*)Ain;
      float4 v0 = make_float4(0.f,0.f,0.f,0.f), v1 = v0;
      if (gr < n){
        v0 = *(const float4*)(A + (size_t)gr * 128 + c);
        v1 = *(const float4*)(A + (size_t)gr * 128 + c + 4);
      }
      tmp[0]=f2bf(v0.x); tmp[1]=f2bf(v0.y); tmp[2]=f2bf(v0.z); tmp[3]=f2bf(v0.w);
      tmp[4]=f2bf(v1.x); tmp[5]=f2bf(v1.y); tmp[6]=f2bf(v1.z); tmp[7]=f2bf(v1.w);
    } else {
      const unsigned short* A = (const unsigned short*)Ain;
      short8 v = {};
      if (gr < n) v = *(const short8*)(A + (size_t)gr * 128 + c);
      *(short8*)tmp = v;
    }
    int g = (c >> 3) ^ (r & 7);
    *(short8*)((char*)At + r * 256 + g * 16) = *(const short8*)tmp;
  }

  bf16x8 bfr[4];
  #pragma unroll
  for (int kk = 0; kk < 4; kk++){
    short8 tmp;
    #pragma unroll
    for (int j = 0; j < 8; j++){
      float wv = W[(kk * 32 + lg * 8 + j) * 128 + (w * 16 + ln)];
      tmp[j] = (short)f2bf(wv);
    }
    bfr[kk] = __builtin_bit_cast(bf16x8, tmp);
  }

  f32x4 acc[8];
  #pragma unroll
  for (int m = 0; m < 8; m++) acc[m] = (f32x4){0.f,0.f,0.f,0.f};

  __syncthreads();

  #pragma unroll
  for (int m = 0; m < 8; m++){
    int row = m * 16 + ln;
    #pragma unroll
    for (int kk = 0; kk < 4; kk++){
      int g = (kk * 4 + lg) ^ (row & 7);
      short8 av = *(const short8*)((const char*)At + row * 256 + g * 16);
      acc[m] = __builtin_amdgcn_mfma_f32_16x16x32_bf16(
          __builtin_bit_cast(bf16x8, av), bfr[kk], acc[m], 0, 0, 0);
    }
  }

  __syncthreads();
  unsigned char* At8 = (unsigned char*)At;

  #pragma unroll
  for (int m = 0; m < 8; m++){
    #pragma unroll
    for (int r = 0; r < 4; r++){
      int row = m * 16 + lg * 4 + r;
      At8[row * 136 + w * 16 + ln] = f2e4m3(dl[row] * acc[m][r]);
    }
  }
  __syncthreads();

  {
    int r = t >> 2, c = (t & 3) * 32;
    int gr = rowBase + r;
    if (gr < n){
      uint4 a = *(const uint4*)(At8 + r * 136 + c);
      uint4 b = *(const uint4*)(At8 + r * 136 + c + 16);
      *(uint4*)(G8 + (size_t)gr * 128 + c)      = a;
      *(uint4*)(G8 + (size_t)gr * 128 + c + 16) = b;
    }
  }
}

// ---------------- SpMM: H(bf16) = relu( dinv*(gather-sum fp8) + b ) ----------------
// 2 dst rows per wave (lanes 0-31 / 32-63); fp8 row = 128B = 32 lanes x dword.

__global__ __launch_bounds__(256) void k_spmm(const unsigned* __restrict__ G8, const int* __restrict__ rowptr,
    const int* __restrict__ colv, const float* __restrict__ dinv, const float* __restrict__ bias,
    unsigned* __restrict__ H, int n)
{
  int wv   = (blockIdx.x * 256 + threadIdx.x) >> 6;
  int lane = threadIdx.x & 63;
  int half = lane >> 5, l5 = lane & 31;
  int row  = wv * 2 + half;
  if (row >= n) return;

  float4 acc = e4m3x4_to_f32(G8[(size_t)row * 32 + l5]);   // self loop
  int e = rowptr[row], e1 = rowptr[row + 1];
  for (; e + 4 <= e1; e += 4){
    int s0 = colv[e], s1 = colv[e + 1], s2 = colv[e + 2], s3 = colv[e + 3];
    unsigned a = G8[(size_t)s0 * 32 + l5];
    unsigned b = G8[(size_t)s1 * 32 + l5];
    unsigned c = G8[(size_t)s2 * 32 + l5];
    unsigned d = G8[(size_t)s3 * 32 + l5];
    float4 fa = e4m3x4_to_f32(a), fb = e4m3x4_to_f32(b);
    float4 fc = e4m3x4_to_f32(c), fd = e4m3x4_to_f32(d);
    acc.x += fa.x + fb.x + fc.x + fd.x;
    acc.y += fa.y + fb.y + fc.y + fd.y;
    acc.z += fa.z + fb.z + fc.z + fd.z;
    acc.w += fa.w + fb.w + fc.w + fd.w;
  }
  for (; e < e1; ++e){
    float4 fa = e4m3x4_to_f32(G8[(size_t)colv[e] * 32 + l5]);
    acc.x += fa.x; acc.y += fa.y; acc.z += fa.z; acc.w += fa.w;
  }
  float dv = dinv[row];
  float4 bi = *(const float4*)(bias + l5 * 4);
  float r0 = fmaxf(fmaf(dv, acc.x, bi.x), 0.f);
  float r1 = fmaxf(fmaf(dv, acc.y, bi.y), 0.f);
  float r2 = fmaxf(fmaf(dv, acc.z, bi.z), 0.f);
  float r3 = fmaxf(fmaf(dv, acc.w, bi.w), 0.f);
  uint2 o;
  o.x = (unsigned)f2bf(r0) | ((unsigned)f2bf(r1) << 16);
  o.y = (unsigned)f2bf(r2) | ((unsigned)f2bf(r3) << 16);
  *(uint2*)(H + (size_t)row * 64 + l5 * 2) = o;
}

// ---------------- layer 3 ----------------

__global__ __launch_bounds__(256) void k_gemv3(const unsigned* __restrict__ H, const float* __restrict__ W3,
    const float* __restrict__ dinv, float* __restrict__ tvec, int n)
{
  int wid  = (blockIdx.x * 256 + threadIdx.x) >> 6;
  int lane = threadIdx.x & 63;
  if (wid >= n) return;
  unsigned u = H[(size_t)wid * 64 + lane];
  float2 wv = *(const float2*)(W3 + lane * 2);
  float v = bflo(u) * wv.x + bfhi(u) * wv.y;
  #pragma unroll
  for (int off = 32; off; off >>= 1) v += __shfl_xor(v, off);
  if (lane == 0) tvec[wid] = dinv[wid] * v;
}

__global__ __launch_bounds__(256) void k_final3(const float* __restrict__ tvec, const int* __restrict__ rowptr,
    const int* __restrict__ colv, const float* __restrict__ dinv, const float* __restrict__ b3,
    const float* __restrict__ x, float* __restrict__ out, int n)
{
  int i = blockIdx.x * 256 + threadIdx.x;
  if (i >= n) return;
  float s = tvec[i];
  int e = rowptr[i], e1 = rowptr[i + 1];
  for (; e < e1; ++e) s += tvec[colv[e]];
  float v = fmaxf(fmaf(dinv[i], s, b3[0]), 0.f);
  out[i] = v + x[(size_t)i * 128 + 127];
}

// ---------------- launch ----------------

extern "C" void kernel_launch(void* const* d_in, const int* in_sizes, int n_in,
                              void* d_out, int out_size, void* d_ws, size_t ws_size,
                              hipStream_t stream)
{
  const float* x  = (const float*)d_in[0];
  const int*   ei = (const int*)d_in[1];
  const float* W1 = (const float*)d_in[3];
  const float* b1 = (const float*)d_in[4];
  const float* W2 = (const float*)d_in[5];
  const float* b2 = (const float*)d_in[6];
  const float* W3 = (const float*)d_in[7];
  const float* b3 = (const float*)d_in[8];
  float* out = (float*)d_out;

  const int N = in_sizes[0] / 128;
  const int E = in_sizes[1] / 2;
  const int* src = ei;
  const int* dst = ei + E;
  const int NB = (N + 127) >> 7;

  char* wsb = (char*)d_ws;
  size_t off = 0;
  auto carve = [&](size_t bytes) -> void* {
    void* p = wsb + off;
    off += bytes;
    off = (off + 255) & ~(size_t)255;
    return p;
  };
  float*    dinv   = (float*)carve((size_t)N * 4);
  int*      rowptr = (int*)carve((size_t)(N + 1) * 4);
  int*      colv   = (int*)carve((size_t)E * 4);
  int*      bcnt   = (int*)carve((size_t)NB * 4);
  int*      bstart = (int*)carve((size_t)(NB + 1) * 4);
  int*      bpos   = (int*)carve((size_t)NB * 4);
  float*    tvec   = (float*)carve((size_t)N * 4);
  unsigned char* G8 = (unsigned char*)carve((size_t)N * 128);  // fp8 N x 128
  unsigned* H      = (unsigned*)carve((size_t)N * 256);        // bf16 N x 128
  unsigned* ebuf   = (unsigned*)H;                             // overlay: dead before spmm1 writes H

  hipMemsetAsync(bcnt, 0, (size_t)NB * 4, stream);
  k_bcnt  <<<128, 1024, 0, stream>>>(dst, bcnt, E, NB);
  k_bscan <<<1, 1024, 0, stream>>>(bcnt, bstart, bpos, rowptr, NB, N, E);
  k_part  <<<(E + PART_C - 1) / PART_C, 1024, 0, stream>>>(src, dst, bpos, ebuf, E, NB);
  k_bsort <<<NB, 256, 0, stream>>>(ebuf, bstart, rowptr, colv, dinv, N);

  // layer 1
  k_gemm_mfma<true ><<<(N + 127) / 128, 512, 0, stream>>>(x, W1, dinv, G8, N);
  k_spmm<<<(N + 7) / 8, 256, 0, stream>>>((const unsigned*)G8, rowptr, colv, dinv, b1, H, N);
  // layer 2
  k_gemm_mfma<false><<<(N + 127) / 128, 512, 0, stream>>>(H, W2, dinv, G8, N);
  k_spmm<<<(N + 7) / 8, 256, 0, stream>>>((const unsigned*)G8, rowptr, colv, dinv, b2, H, N);
  // layer 3 (HID -> 1)
  k_gemv3 <<<(N + 3) / 4, 256, 0, stream>>>(H, W3, dinv, tvec, N);
  k_final3<<<(N + 255) / 256, 256, 0, stream>>>(tvec, rowptr, colv, dinv, b3, x, out, N);
}

// Round 6
// 178.164 us; speedup vs baseline: 3.2616x; 1.1292x over previous
//
#include <hip/hip_runtime.h>
#include <hip/hip_bf16.h>

typedef __attribute__((ext_vector_type(8))) short short8;
typedef __attribute__((ext_vector_type(8))) __bf16 bf16x8;
typedef __attribute__((ext_vector_type(4))) float f32x4;

static __device__ __forceinline__ float bflo(unsigned u){ return __uint_as_float(u << 16); }
static __device__ __forceinline__ float bfhi(unsigned u){ return __uint_as_float(u & 0xffff0000u); }
static __device__ __forceinline__ unsigned short f2bf(float f){
  unsigned u = __float_as_uint(f);
  unsigned r = u + 0x7fffu + ((u >> 16) & 1u);
  return (unsigned short)(r >> 16);
}

// ---- fp8 e4m3 conversions (HW via builtins; self-consistent SW fallback) ----
#if __has_builtin(__builtin_amdgcn_cvt_pk_fp8_f32)
static __device__ __forceinline__ unsigned char f2e4m3(float f){
  return (unsigned char)(__builtin_amdgcn_cvt_pk_fp8_f32(f, 0.f, 0, false) & 0xff);
}
#else
static __device__ __forceinline__ unsigned char f2e4m3(float f){
  unsigned s = (__float_as_uint(f) >> 31) << 7;
  float a = fabsf(f);
  if (a >= 448.f) return (unsigned char)(s | 0x7e);
  if (a < 0.0009765625f) return (unsigned char)s;
  if (a >= 0.015625f){
    int e; float m = frexpf(a, &e);
    int q = (int)rintf(m * 16.f);
    int E = e - 1 + 7;
    if (q == 16){ q = 8; E++; }
    if (E >= 16) return (unsigned char)(s | 0x7e);
    return (unsigned char)(s | (E << 3) | (q - 8));
  } else {
    int q = (int)rintf(a * 512.f);
    if (q > 7) return (unsigned char)(s | 0x08);
    return (unsigned char)(s | q);
  }
}
#endif

#if __has_builtin(__builtin_amdgcn_cvt_pk_f32_fp8)
static __device__ __forceinline__ float4 e4m3x4_to_f32(unsigned u){
  auto lo = __builtin_amdgcn_cvt_pk_f32_fp8((int)u, false);
  auto hi = __builtin_amdgcn_cvt_pk_f32_fp8((int)u, true);
  return make_float4(lo[0], lo[1], hi[0], hi[1]);
}
#else
static __device__ __forceinline__ float e4m3_1(unsigned b){
  unsigned s = b >> 7, e = (b >> 3) & 15, m = b & 7;
  float v = e ? ldexpf((float)(8 + m) * 0.125f, (int)e - 7) : ldexpf((float)m * 0.125f, -6);
  return s ? -v : v;
}
static __device__ __forceinline__ float4 e4m3x4_to_f32(unsigned u){
  return make_float4(e4m3_1(u & 255), e4m3_1((u >> 8) & 255), e4m3_1((u >> 16) & 255), e4m3_1(u >> 24));
}
#endif

static __device__ __forceinline__ void add8(float* acc, uint2 u){
  float4 a = e4m3x4_to_f32(u.x), b = e4m3x4_to_f32(u.y);
  acc[0] += a.x; acc[1] += a.y; acc[2] += a.z; acc[3] += a.w;
  acc[4] += b.x; acc[5] += b.y; acc[6] += b.z; acc[7] += b.w;
}

#define NBMAX  1024
#define PART_C 4096
#define STCAP  4096

// ---------------- bucket pipeline ----------------

__global__ __launch_bounds__(1024) void k_bcnt(const int* __restrict__ dst, int* __restrict__ bcnt,
                                               int E, int NB){
  __shared__ int h[NBMAX];
  const int t = threadIdx.x;
  for (int i = t; i < NB; i += 1024) h[i] = 0;
  __syncthreads();
  for (int e = blockIdx.x * 1024 + t; e < E; e += gridDim.x * 1024)
    atomicAdd(&h[dst[e] >> 7], 1);
  __syncthreads();
  for (int i = t; i < NB; i += 1024) if (h[i]) atomicAdd(&bcnt[i], h[i]);
}

__global__ __launch_bounds__(1024) void k_bscan(const int* __restrict__ bcnt, int* __restrict__ bstart,
    int* __restrict__ bpos, int* __restrict__ rowptr, int NB, int N, int E){
  __shared__ int sc[1024];
  const int t = threadIdx.x;
  int v = (t < NB) ? bcnt[t] : 0;
  sc[t] = v; __syncthreads();
  for (int off = 1; off < 1024; off <<= 1){
    int u = (t >= off) ? sc[t - off] : 0;
    __syncthreads();
    sc[t] += u;
    __syncthreads();
  }
  int excl = sc[t] - v;
  if (t < NB){ bstart[t] = excl; bpos[t] = excl; }
  if (t == 0){ bstart[NB] = E; rowptr[N] = E; }
}

__global__ __launch_bounds__(1024) void k_part(const int* __restrict__ src, const int* __restrict__ dst,
    int* __restrict__ bpos, unsigned* __restrict__ ebuf, int E, int NB)
{
  __shared__ int hist[NBMAX + 1];
  __shared__ int hist2[NBMAX];
  __shared__ int gbase[NBMAX];
  __shared__ int sc[1024];
  __shared__ unsigned staged[PART_C];

  const int t = threadIdx.x;
  const int base = blockIdx.x * PART_C;

  for (int i = t; i < NBMAX; i += 1024){ hist[i] = 0; hist2[i] = 0; }
  __syncthreads();

  unsigned up[4];
  int bb[4];
  #pragma unroll
  for (int j = 0; j < 4; j++){
    int e = base + j * 1024 + t;
    if (e < E){
      int s = src[e], d = dst[e];
      bb[j] = d >> 7;
      up[j] = ((unsigned)s << 7) | (unsigned)(d & 127);
      atomicAdd(&hist[bb[j]], 1);
    } else bb[j] = -1;
  }
  __syncthreads();

  int v = (t < NB) ? hist[t] : 0;
  sc[t] = v; __syncthreads();
  for (int off = 1; off < 1024; off <<= 1){
    int u = (t >= off) ? sc[t - off] : 0;
    __syncthreads();
    sc[t] += u;
    __syncthreads();
  }
  int incl = sc[t];
  if (t < NB) hist[t] = incl - v;
  if (t == NB - 1) hist[NB] = incl;
  if (t < NB && v > 0) gbase[t] = atomicAdd(&bpos[t], v);
  __syncthreads();

  #pragma unroll
  for (int j = 0; j < 4; j++){
    if (bb[j] >= 0){
      int r = atomicAdd(&hist2[bb[j]], 1);
      staged[hist[bb[j]] + r] = up[j];
    }
  }
  __syncthreads();

  int total = hist[NB];
  for (int i = t; i < total; i += 1024){
    int lo = 0, hi = NB;
    while (hi - lo > 1){
      int mid = (lo + hi) >> 1;
      if (hist[mid] <= i) lo = mid; else hi = mid;
    }
    ebuf[gbase[lo] + (i - hist[lo])] = staged[i];
  }
}

__global__ __launch_bounds__(256) void k_bsort(const unsigned* __restrict__ ebuf, const int* __restrict__ bstart,
    int* __restrict__ rowptr, int* __restrict__ colv, float* __restrict__ dinv, int n)
{
  __shared__ int cl[128];
  __shared__ int sc2[256];
  __shared__ unsigned stg[STCAP];

  const int t = threadIdx.x;
  const int b = blockIdx.x;
  const int r0 = b << 7;
  const int beg = bstart[b];
  const int end = bstart[b + 1];
  const int total = end - beg;

  if (t < 128) cl[t] = 0;
  __syncthreads();
  for (int i = beg + t; i < end; i += 256) atomicAdd(&cl[ebuf[i] & 127u], 1);
  __syncthreads();

  int v = (t < 128) ? cl[t] : 0;
  sc2[t] = v; __syncthreads();
  for (int off = 1; off < 256; off <<= 1){
    int u = (t >= off) ? sc2[t - off] : 0;
    __syncthreads();
    sc2[t] += u;
    __syncthreads();
  }
  int excl = sc2[t] - v;
  if (t < 128){
    int node = r0 + t;
    if (node < n){
      rowptr[node] = beg + excl;
      dinv[node]   = rsqrtf((float)(v + 1));
    }
    cl[t] = excl;
  }
  __syncthreads();

  if (total <= STCAP){
    for (int i = beg + t; i < end; i += 256){
      unsigned u = ebuf[i];
      int p = atomicAdd(&cl[u & 127u], 1);
      stg[p] = u >> 7;
    }
    __syncthreads();
    for (int i = t; i < total; i += 256) colv[beg + i] = (int)stg[i];
  } else {
    for (int i = beg + t; i < end; i += 256){
      unsigned u = ebuf[i];
      int p = atomicAdd(&cl[u & 127u], 1);
      colv[beg + p] = (int)(u >> 7);
    }
  }
}

// ---------------- MFMA GEMM: G8[i,:] = fp8( dinv[i] * (A[i,:] @ W) ) ----------------

template<bool AF32>
__global__ __launch_bounds__(512) void k_gemm_mfma(const void* __restrict__ Ain, const float* __restrict__ W,
    const float* __restrict__ dinv, unsigned char* __restrict__ G8, int n)
{
  __shared__ unsigned short At[128 * 136];
  __shared__ float dl[128];

  const int t = threadIdx.x;
  const int rowBase = blockIdx.x * 128;
  const int w  = t >> 6;
  const int l  = t & 63;
  const int ln = l & 15;
  const int lg = l >> 4;

  if (t < 128){
    int gr = rowBase + t;
    dl[t] = (gr < n) ? dinv[gr] : 0.f;
  }

  #pragma unroll
  for (int i = 0; i < 4; i++){
    int flat = i * 4096 + t * 8;
    int r = flat >> 7, c = flat & 127;
    int gr = rowBase + r;
    unsigned short tmp[8];
    if constexpr (AF32){
      const float* A = (const float*)Ain;
      float4 v0 = make_float4(0.f,0.f,0.f,0.f), v1 = v0;
      if (gr < n){
        v0 = *(const float4*)(A + (size_t)gr * 128 + c);
        v1 = *(const float4*)(A + (size_t)gr * 128 + c + 4);
      }
      tmp[0]=f2bf(v0.x); tmp[1]=f2bf(v0.y); tmp[2]=f2bf(v0.z); tmp[3]=f2bf(v0.w);
      tmp[4]=f2bf(v1.x); tmp[5]=f2bf(v1.y); tmp[6]=f2bf(v1.z); tmp[7]=f2bf(v1.w);
    } else {
      const unsigned short* A = (const unsigned short*)Ain;
      short8 v = {};
      if (gr < n) v = *(const short8*)(A + (size_t)gr * 128 + c);
      *(short8*)tmp = v;
    }
    int g = (c >> 3) ^ (r & 7);
    *(short8*)((char*)At + r * 256 + g * 16) = *(const short8*)tmp;
  }

  bf16x8 bfr[4];
  #pragma unroll
  for (int kk = 0; kk < 4; kk++){
    short8 tmp;
    #pragma unroll
    for (int j = 0; j < 8; j++){
      float wv = W[(kk * 32 + lg * 8 + j) * 128 + (w * 16 + ln)];
      tmp[j] = (short)f2bf(wv);
    }
    bfr[kk] = __builtin_bit_cast(bf16x8, tmp);
  }

  f32x4 acc[8];
  #pragma unroll
  for (int m = 0; m < 8; m++) acc[m] = (f32x4){0.f,0.f,0.f,0.f};

  __syncthreads();

  #pragma unroll
  for (int m = 0; m < 8; m++){
    int row = m * 16 + ln;
    #pragma unroll
    for (int kk = 0; kk < 4; kk++){
      int g = (kk * 4 + lg) ^ (row & 7);
      short8 av = *(const short8*)((const char*)At + row * 256 + g * 16);
      acc[m] = __builtin_amdgcn_mfma_f32_16x16x32_bf16(
          __builtin_bit_cast(bf16x8, av), bfr[kk], acc[m], 0, 0, 0);
    }
  }

  __syncthreads();
  unsigned char* At8 = (unsigned char*)At;

  #pragma unroll
  for (int m = 0; m < 8; m++){
    #pragma unroll
    for (int r = 0; r < 4; r++){
      int row = m * 16 + lg * 4 + r;
      At8[row * 136 + w * 16 + ln] = f2e4m3(dl[row] * acc[m][r]);
    }
  }
  __syncthreads();

  {
    int r = t >> 2, c = (t & 3) * 32;
    int gr = rowBase + r;
    if (gr < n){
      uint4 a = *(const uint4*)(At8 + r * 136 + c);
      uint4 b = *(const uint4*)(At8 + r * 136 + c + 16);
      *(uint4*)(G8 + (size_t)gr * 128 + c)      = a;
      *(uint4*)(G8 + (size_t)gr * 128 + c + 16) = b;
    }
  }
}

// ---------------- SpMM: H(bf16) = relu( dinv*(gather-sum fp8) + b ) ----------------
// 16 lanes per row (uint2 = 8 fp8/lane); 4 rows per wave; unroll tiers 8/4/1.

__global__ __launch_bounds__(256) void k_spmm(const uint2* __restrict__ G8, const int* __restrict__ rowptr,
    const int* __restrict__ colv, const float* __restrict__ dinv, const float* __restrict__ bias,
    unsigned* __restrict__ H, int n)
{
  int tid = blockIdx.x * 256 + threadIdx.x;
  int row = tid >> 4;
  int gl  = tid & 15;
  if (row >= n) return;

  float acc[8] = {0,0,0,0,0,0,0,0};
  add8(acc, G8[(size_t)row * 16 + gl]);         // self loop
  int e = rowptr[row], e1 = rowptr[row + 1];

  for (; e + 8 <= e1; e += 8){
    int s0 = colv[e    ], s1 = colv[e + 1], s2 = colv[e + 2], s3 = colv[e + 3];
    int s4 = colv[e + 4], s5 = colv[e + 5], s6 = colv[e + 6], s7 = colv[e + 7];
    uint2 v0 = G8[(size_t)s0 * 16 + gl];
    uint2 v1 = G8[(size_t)s1 * 16 + gl];
    uint2 v2 = G8[(size_t)s2 * 16 + gl];
    uint2 v3 = G8[(size_t)s3 * 16 + gl];
    uint2 v4 = G8[(size_t)s4 * 16 + gl];
    uint2 v5 = G8[(size_t)s5 * 16 + gl];
    uint2 v6 = G8[(size_t)s6 * 16 + gl];
    uint2 v7 = G8[(size_t)s7 * 16 + gl];
    add8(acc, v0); add8(acc, v1); add8(acc, v2); add8(acc, v3);
    add8(acc, v4); add8(acc, v5); add8(acc, v6); add8(acc, v7);
  }
  for (; e + 4 <= e1; e += 4){
    int s0 = colv[e], s1 = colv[e + 1], s2 = colv[e + 2], s3 = colv[e + 3];
    uint2 v0 = G8[(size_t)s0 * 16 + gl];
    uint2 v1 = G8[(size_t)s1 * 16 + gl];
    uint2 v2 = G8[(size_t)s2 * 16 + gl];
    uint2 v3 = G8[(size_t)s3 * 16 + gl];
    add8(acc, v0); add8(acc, v1); add8(acc, v2); add8(acc, v3);
  }
  for (; e < e1; ++e) add8(acc, G8[(size_t)colv[e] * 16 + gl]);

  float dv = dinv[row];
  float4 b0 = *(const float4*)(bias + gl * 8);
  float4 b1 = *(const float4*)(bias + gl * 8 + 4);
  float r0 = fmaxf(fmaf(dv, acc[0], b0.x), 0.f);
  float r1 = fmaxf(fmaf(dv, acc[1], b0.y), 0.f);
  float r2 = fmaxf(fmaf(dv, acc[2], b0.z), 0.f);
  float r3 = fmaxf(fmaf(dv, acc[3], b0.w), 0.f);
  float r4 = fmaxf(fmaf(dv, acc[4], b1.x), 0.f);
  float r5 = fmaxf(fmaf(dv, acc[5], b1.y), 0.f);
  float r6 = fmaxf(fmaf(dv, acc[6], b1.z), 0.f);
  float r7 = fmaxf(fmaf(dv, acc[7], b1.w), 0.f);
  uint4 o;
  o.x = (unsigned)f2bf(r0) | ((unsigned)f2bf(r1) << 16);
  o.y = (unsigned)f2bf(r2) | ((unsigned)f2bf(r3) << 16);
  o.z = (unsigned)f2bf(r4) | ((unsigned)f2bf(r5) << 16);
  o.w = (unsigned)f2bf(r6) | ((unsigned)f2bf(r7) << 16);
  *(uint4*)(H + (size_t)row * 64 + gl * 4) = o;
}

// ---------------- layer 3 ----------------

__global__ __launch_bounds__(256) void k_gemv3(const unsigned* __restrict__ H, const float* __restrict__ W3,
    const float* __restrict__ dinv, float* __restrict__ tvec, int n)
{
  int wid  = (blockIdx.x * 256 + threadIdx.x) >> 6;
  int lane = threadIdx.x & 63;
  if (wid >= n) return;
  unsigned u = H[(size_t)wid * 64 + lane];
  float2 wv = *(const float2*)(W3 + lane * 2);
  float v = bflo(u) * wv.x + bfhi(u) * wv.y;
  #pragma unroll
  for (int off = 32; off; off >>= 1) v += __shfl_xor(v, off);
  if (lane == 0) tvec[wid] = dinv[wid] * v;
}

// 16 lanes per row: parallel tvec gather + shfl reduce
__global__ __launch_bounds__(256) void k_final3(const float* __restrict__ tvec, const int* __restrict__ rowptr,
    const int* __restrict__ colv, const float* __restrict__ dinv, const float* __restrict__ b3,
    const float* __restrict__ x, float* __restrict__ out, int n)
{
  int tid = blockIdx.x * 256 + threadIdx.x;
  int row = tid >> 4;
  int gl  = tid & 15;
  if (row >= n) return;
  float s = 0.f;
  int e0 = rowptr[row], e1 = rowptr[row + 1];
  for (int e = e0 + gl; e < e1; e += 16) s += tvec[colv[e]];
  s += __shfl_xor(s, 1); s += __shfl_xor(s, 2);
  s += __shfl_xor(s, 4); s += __shfl_xor(s, 8);
  if (gl == 0){
    s += tvec[row];                              // self loop
    float v = fmaxf(fmaf(dinv[row], s, b3[0]), 0.f);
    out[row] = v + x[(size_t)row * 128 + 127];
  }
}

// ---------------- launch ----------------

extern "C" void kernel_launch(void* const* d_in, const int* in_sizes, int n_in,
                              void* d_out, int out_size, void* d_ws, size_t ws_size,
                              hipStream_t stream)
{
  const float* x  = (const float*)d_in[0];
  const int*   ei = (const int*)d_in[1];
  const float* W1 = (const float*)d_in[3];
  const float* b1 = (const float*)d_in[4];
  const float* W2 = (const float*)d_in[5];
  const float* b2 = (const float*)d_in[6];
  const float* W3 = (const float*)d_in[7];
  const float* b3 = (const float*)d_in[8];
  float* out = (float*)d_out;

  const int N = in_sizes[0] / 128;
  const int E = in_sizes[1] / 2;
  const int* src = ei;
  const int* dst = ei + E;
  const int NB = (N + 127) >> 7;

  char* wsb = (char*)d_ws;
  size_t off = 0;
  auto carve = [&](size_t bytes) -> void* {
    void* p = wsb + off;
    off += bytes;
    off = (off + 255) & ~(size_t)255;
    return p;
  };
  float*    dinv   = (float*)carve((size_t)N * 4);
  int*      rowptr = (int*)carve((size_t)(N + 1) * 4);
  int*      colv   = (int*)carve((size_t)E * 4);
  int*      bcnt   = (int*)carve((size_t)NB * 4);
  int*      bstart = (int*)carve((size_t)(NB + 1) * 4);
  int*      bpos   = (int*)carve((size_t)NB * 4);
  float*    tvec   = (float*)carve((size_t)N * 4);
  unsigned char* G8 = (unsigned char*)carve((size_t)N * 128);  // fp8 N x 128
  unsigned* H      = (unsigned*)carve((size_t)N * 256);        // bf16 N x 128
  unsigned* ebuf   = (unsigned*)H;                             // overlay: dead before spmm1 writes H

  hipMemsetAsync(bcnt, 0, (size_t)NB * 4, stream);
  k_bcnt  <<<128, 1024, 0, stream>>>(dst, bcnt, E, NB);
  k_bscan <<<1, 1024, 0, stream>>>(bcnt, bstart, bpos, rowptr, NB, N, E);
  k_part  <<<(E + PART_C - 1) / PART_C, 1024, 0, stream>>>(src, dst, bpos, ebuf, E, NB);
  k_bsort <<<NB, 256, 0, stream>>>(ebuf, bstart, rowptr, colv, dinv, N);

  // layer 1
  k_gemm_mfma<true ><<<(N + 127) / 128, 512, 0, stream>>>(x, W1, dinv, G8, N);
  k_spmm<<<((size_t)N * 16 + 255) / 256, 256, 0, stream>>>((const uint2*)G8, rowptr, colv, dinv, b1, H, N);
  // layer 2
  k_gemm_mfma<false><<<(N + 127) / 128, 512, 0, stream>>>(H, W2, dinv, G8, N);
  k_spmm<<<((size_t)N * 16 + 255) / 256, 256, 0, stream>>>((const uint2*)G8, rowptr, colv, dinv, b2, H, N);
  // layer 3 (HID -> 1)
  k_gemv3 <<<(N + 3) / 4, 256, 0, stream>>>(H, W3, dinv, tvec, N);
  k_final3<<<((size_t)N * 16 + 255) / 256, 256, 0, stream>>>(tvec, rowptr, colv, dinv, b3, x, out, N);
}